// Round 9
// baseline (304.713 us; speedup 1.0000x reference)
//
#include <hip/hip_runtime.h>
#include <cstdint>

typedef unsigned short u16;
typedef __attribute__((ext_vector_type(8))) short bf16x8;
typedef __attribute__((ext_vector_type(4))) float f32x4;
typedef __attribute__((ext_vector_type(4))) unsigned short u16x4;

#define AS_G __attribute__((address_space(1)))
#define AS_L __attribute__((address_space(3)))

__device__ __forceinline__ void gl_lds16(const u16* g, u16* l) {
  // async global->LDS, 16B/lane; LDS dest = wave-uniform base + lane*16
  __builtin_amdgcn_global_load_lds((const AS_G unsigned int*)g, (AS_L unsigned int*)l, 16, 0, 0);
}
__device__ __forceinline__ float bf2f(u16 u) {
  union { unsigned int i; float f; } v; v.i = ((unsigned int)u) << 16; return v.f;
}
__device__ __forceinline__ u16 f2bf(float f) {
  union { float f; unsigned int i; } v; v.f = f;
  unsigned int x = v.i;
  return (u16)((x + 0x7fffu + ((x >> 16) & 1u)) >> 16);  // RNE
}

// ---------------- fp32 -> bf16 convert of q/k/v ----------------
__global__ __launch_bounds__(256) void convert_kernel(
    const float* __restrict__ q, const float* __restrict__ k, const float* __restrict__ v,
    u16* __restrict__ qb, u16* __restrict__ kb, u16* __restrict__ vb)
{
  const int id = blockIdx.y;
  const float* s = (id == 0) ? q : (id == 1) ? k : v;
  u16* d = (id == 0) ? qb : (id == 1) ? kb : vb;
  const int o = (blockIdx.x * 256 + threadIdx.x) * 4;
  const f32x4 x = *(const f32x4*)(s + o);
  u16x4 y;
#pragma unroll
  for (int i = 0; i < 4; ++i) y[i] = f2bf(x[i]);
  *(u16x4*)(d + o) = y;
}

// ---------------- weight pre-transpose (fp32 src -> bf16 dst) ----------------
__global__ __launch_bounds__(256) void transpose_kernel(
    const float* __restrict__ s0, const float* __restrict__ s1, const float* __restrict__ s2,
    const float* __restrict__ s3, const float* __restrict__ s4, u16* __restrict__ wdst)
{
  const int id = blockIdx.y;
  const float* src; u16* dst; int rb, total;
  switch (id) {
    case 0:  src = s0; dst = wdst;           rb = 8;  total = 524288; break;
    case 1:  src = s1; dst = wdst + 524288;  rb = 8;  total = 524288; break;
    case 2:  src = s2; dst = wdst + 1048576; rb = 8;  total = 524288; break;
    case 3:  src = s3; dst = wdst + 1572864; rb = 11; total = 524288; break;
    default: src = s4; dst = wdst + 2097152; rb = 8;  total = 65536;  break;
  }
  const int o = blockIdx.x * 256 + threadIdx.x;
  if (o >= total) return;
  const int C_ = total >> rb;
  const int c = o >> rb, r = o & ((1 << rb) - 1);
  dst[o] = f2bf(src[r * C_ + c]);
}

// ---------------- QKV projection on the UNGATHERED 8192 rows ----------------
// R2 structure (best measured: 64.4 us).
__global__ __launch_bounds__(256) void proj_kernel(
    const u16* __restrict__ qb, const u16* __restrict__ kb, const u16* __restrict__ vb,
    const u16* __restrict__ wts, const float* __restrict__ bq, const float* __restrict__ bk,
    const float* __restrict__ bv, u16* __restrict__ Pq, u16* __restrict__ Pk,
    u16* __restrict__ Pv)
{
  __shared__ u16 lds[16384];            // buf b at [b*8192): A [0,4096)+B [4096,8192); epilogue: 64x136 per half
  const int t = threadIdx.x;
  const int w = t >> 6, lane = t & 63, quad = lane >> 4, lc = lane & 15;
  const int wy = w >> 1, wx = w & 1;
  // swizzle: same-by blocks (sharing the A slab) are XCD-local.
  const int flat = blockIdx.x + (blockIdx.y << 4);   // 0..1023
  const int tn = flat >> 6, by = flat & 63, z = blockIdx.z;
  const u16* A0 = ((z == 0) ? qb : (z == 1) ? kb : vb) + by * 32768;   // 128 rows x 256
  const u16* BT = wts + z * 524288 + tn * 128 * 256;

  const f32x4 fz = {0.f, 0.f, 0.f, 0.f};
  f32x4 acc[4][4];
#pragma unroll
  for (int i = 0; i < 4; ++i)
#pragma unroll
    for (int j = 0; j < 4; ++j) acc[i][j] = fz;

#define PROJ_STAGE(ck, b) do {                                         \
    const int ko_ = (ck) * 32 + w * 8;                                 \
    u16* Lb_ = &lds[(b) * 8192];                                       \
    gl_lds16(A0 + lane * 256 + ko_,        Lb_ + w * 1024);            \
    gl_lds16(A0 + (64 + lane) * 256 + ko_, Lb_ + w * 1024 + 512);      \
    gl_lds16(BT + lane * 256 + ko_,        Lb_ + 4096 + w * 1024);     \
    gl_lds16(BT + (64 + lane) * 256 + ko_, Lb_ + 4096 + w * 1024 + 512); \
  } while (0)

  PROJ_STAGE(0, 0);
#pragma unroll
  for (int ck = 0; ck < 8; ++ck) {
    const int cur = ck & 1;
    if (ck < 7) {
      PROJ_STAGE(ck + 1, cur ^ 1);
      asm volatile("s_waitcnt vmcnt(4)" ::: "memory");   // own chunk-ck loads landed; prefetch stays in flight
    } else {
      asm volatile("s_waitcnt vmcnt(0)" ::: "memory");
    }
    __builtin_amdgcn_s_barrier();                        // all waves' chunk-ck loads landed
    asm volatile("" ::: "memory");
    const u16* Ab = &lds[cur * 8192];
    const u16* Bb = &lds[cur * 8192 + 4096];
    bf16x8 af[4], bfg[4];
#pragma unroll
    for (int mi = 0; mi < 4; ++mi)
      af[mi] = *(const bf16x8*)&Ab[quad * 1024 + (wy * 64 + mi * 16 + lc) * 8];
#pragma unroll
    for (int ni = 0; ni < 4; ++ni)
      bfg[ni] = *(const bf16x8*)&Bb[quad * 1024 + (wx * 64 + ni * 16 + lc) * 8];
#pragma unroll
    for (int mi = 0; mi < 4; ++mi)
#pragma unroll
      for (int ni = 0; ni < 4; ++ni)
        acc[mi][ni] = __builtin_amdgcn_mfma_f32_16x16x32_bf16(af[mi], bfg[ni], acc[mi][ni], 0, 0, 0);
    asm volatile("s_waitcnt lgkmcnt(0)" ::: "memory");   // all ds_reads of buf[cur] done
    __builtin_amdgcn_s_barrier();                        // safe to overwrite buf[cur] next iter
  }
#undef PROJ_STAGE

  const float* bias = (z == 0) ? bq : (z == 1) ? bk : bv;
  u16* P = ((z == 0) ? Pq : (z == 1) ? Pk : Pv) + by * 262144;

  // Two 64-row epilogue passes; each uses only 64x136 u16 = 17408 B of LDS.
#pragma unroll
  for (int half = 0; half < 2; ++half) {
    __syncthreads();                     // prev pass reads / K-loop staging done
    if (wy == half) {
#pragma unroll
      for (int mi = 0; mi < 4; ++mi)
#pragma unroll
        for (int ni = 0; ni < 4; ++ni) {
          const int col = wx * 64 + ni * 16 + lc;
          const float bi = bias[tn * 128 + col];
#pragma unroll
          for (int r = 0; r < 4; ++r) {
            const int row = mi * 16 + quad * 4 + r;
            lds[row * 136 + col] = f2bf(acc[mi][ni][r] + bi);
          }
        }
    }
    __syncthreads();
#pragma unroll
    for (int p = 0; p < 4; ++p) {        // 256B-contiguous row segments, 16B/lane
      const int e = p * 2048 + t * 8;
      const int row = e >> 7, col0 = e & 127;
      *(bf16x8*)(P + (half * 64 + row) * 2048 + tn * 128 + col0) =
          *(const bf16x8*)&lds[row * 136 + col0];
    }
  }
}

// ---------------- Pv group-slab transpose (coalesced both sides) ----------------
__global__ __launch_bounds__(256) void vtrans_kernel(
    const u16* __restrict__ Pv, u16* __restrict__ VT)
{
  __shared__ u16 lT[4096];
  const int t = threadIdx.x;
  const int tile = blockIdx.x;          // 0..7
  const int g = blockIdx.y;             // 0..511
  const int q0 = (tile & 1) * 64, d0 = (tile >> 1) * 64;
  const u16* src = Pv + g * 32768;      // [q'=128][d=256]
  u16* dst = VT + g * 32768;            // [d=256][q'=128]
#pragma unroll
  for (int it = 0; it < 2; ++it) {
    const int e = it * 2048 + t * 8;
    const int lq = e >> 6, ld0 = e & 63;
    const bf16x8 v = *(const bf16x8*)(src + (q0 + lq) * 256 + d0 + ld0);
    const int kb = ((ld0 >> 3) + lq + (lq >> 3)) & 7;
    *(bf16x8*)&lT[lq * 64 + kb * 8] = v;
  }
  __syncthreads();
#pragma unroll
  for (int it = 0; it < 2; ++it) {
    const int e = it * 2048 + t * 8;
    const int ld = e >> 6, lq0 = e & 63;
    bf16x8 v;
#pragma unroll
    for (int i = 0; i < 8; ++i) {
      const int lq = lq0 + i;
      const int kb = ((ld >> 3) + lq + (lq >> 3)) & 7;
      v[i] = (short)lT[lq * 64 + kb * 8 + (ld & 7)];
    }
    *(bf16x8*)(dst + (d0 + ld) * 128 + q0 + lq0) = v;
  }
}

// ---------------- attention per DISTINCT unit (dedup'd, R7) ----------------
__global__ __launch_bounds__(512) void attn_kernel(
    const u16* __restrict__ Pq, const u16* __restrict__ Pk,
    const u16* __restrict__ VT, u16* __restrict__ Obuf)
{
  __shared__ u16 lKV[16384];
  __shared__ u16 lP[16384];
  const int t = threadIdx.x;
  const int w = t >> 6, lane = t & 63, quad = lane >> 4, lc = lane & 15;
  const int M = blockIdx.x, b = blockIdx.y;
  const int m0 = w * 16;
  const int r0 = b * 1024 + M * 16;
  const u16* Qb = Pq + r0 * 2048;
  const u16* Kb = Pk + r0 * 2048;
  const u16* Vb = VT + (b * 64 + M) * 32768;
  const f32x4 fz = {0.f, 0.f, 0.f, 0.f};

  bf16x8 aq[8];
#pragma unroll
  for (int kc = 0; kc < 8; ++kc)
    aq[kc] = *(const bf16x8*)(Qb + (m0 + lc) * 256 + kc * 32 + quad * 8);

  f32x4 s[8];
  for (int hk = 0; hk < 2; ++hk) {
    __syncthreads();
#pragma unroll
    for (int jj = 0; jj < 4; ++jj)
      gl_lds16(Kb + (hk * 64 + lane) * 256 + w * 32 + jj * 8, &lKV[w * 2048 + jj * 512]);
    __syncthreads();
#pragma unroll
    for (int ntl = 0; ntl < 4; ++ntl) {
      const int nt = hk * 4 + ntl;
      s[nt] = fz;
#pragma unroll
      for (int kc = 0; kc < 8; ++kc) {
        const bf16x8 bfr = *(const bf16x8*)&lKV[kc * 2048 + quad * 512 + (ntl * 16 + lc) * 8];
        s[nt] = __builtin_amdgcn_mfma_f32_16x16x32_bf16(aq[kc], bfr, s[nt], 0, 0, 0);
      }
    }
  }

  const float scale = 0.0625f;
#pragma unroll
  for (int r = 0; r < 4; ++r) {
    float mx = -3.0e38f;
#pragma unroll
    for (int nt = 0; nt < 8; ++nt) mx = fmaxf(mx, s[nt][r]);
    mx = fmaxf(mx, __shfl_xor(mx, 1)); mx = fmaxf(mx, __shfl_xor(mx, 2));
    mx = fmaxf(mx, __shfl_xor(mx, 4)); mx = fmaxf(mx, __shfl_xor(mx, 8));
    mx *= scale;
    float sm = 0.0f;
#pragma unroll
    for (int nt = 0; nt < 8; ++nt) {
      const float e = __expf(s[nt][r] * scale - mx);
      s[nt][r] = e; sm += e;
    }
    sm += __shfl_xor(sm, 1); sm += __shfl_xor(sm, 2);
    sm += __shfl_xor(sm, 4); sm += __shfl_xor(sm, 8);
    const float inv = 1.0f / sm;
    const int q = m0 + quad * 4 + r;
#pragma unroll
    for (int nt = 0; nt < 8; ++nt) {
      const int k = nt * 16 + lc;
      lP[(k >> 5) * 4096 + ((k >> 3) & 3) * 1024 + q * 8 + (k & 7)] = f2bf(s[nt][r] * inv);
    }
  }
  __syncthreads();

  bf16x8 ap[4];
#pragma unroll
  for (int kc2 = 0; kc2 < 4; ++kc2)
    ap[kc2] = *(const bf16x8*)&lP[kc2 * 4096 + quad * 1024 + (m0 + lc) * 8];

  f32x4 o[16];
#pragma unroll
  for (int nt = 0; nt < 16; ++nt) o[nt] = fz;

  for (int hk = 0; hk < 2; ++hk) {
    if (hk) __syncthreads();
#pragma unroll
    for (int jj = 0; jj < 4; ++jj) {
      const int i = w * 4 + jj;
      const int kc2l = i >> 4, cb = (i >> 2) & 3, db = (i & 3) * 64;
      gl_lds16(Vb + (db + lane) * 128 + (hk * 2 + kc2l) * 32 + cb * 8,
               &lKV[kc2l * 8192 + cb * 2048 + db * 8]);
    }
    __syncthreads();
#pragma unroll
    for (int nt = 0; nt < 16; ++nt)
#pragma unroll
      for (int kc2l = 0; kc2l < 2; ++kc2l) {
        const bf16x8 bfr = *(const bf16x8*)&lKV[kc2l * 8192 + quad * 2048 + (nt * 16 + lc) * 8];
        o[nt] = __builtin_amdgcn_mfma_f32_16x16x32_bf16(ap[hk * 2 + kc2l], bfr, o[nt], 0, 0, 0);
      }
  }

  u16* Ob = Obuf + r0 * 2048;           // linear gathered output rows [16M,16M+16)
#pragma unroll
  for (int nt = 0; nt < 16; ++nt)
#pragma unroll
    for (int r = 0; r < 4; ++r) {
      const int q = m0 + quad * 4 + r;
      Ob[q * 256 + nt * 16 + lc] = f2bf(o[nt][r]);
    }
}

// ---------------- fused GEMM + bias + residual + LayerNorm ----------------
// R9 fix vs R8 (75.5 us, MfmaUtil 4%, Occ 21%): 16-row x full-N(256) tiles
// -> 512 blocks (was 256) and LDS ~35.3 KB -> 4 blocks/CU resident (was 1).
// The serial 64-chunk latency chain now interleaves across 4 blocks/CU.
// A chunk = ONE gl_lds16 (wave 0): lane l -> row l&15, kq l>>4 is the linear
// identity l*8 = (l>>4)*128+(l&15)*8. B staging unchanged (2 instr/wave).
// mode 0 (Wo/LN1): resid = f32 value, out = bf16 xbuf, Ktot=2048.
// mode 1 (FF/LN2): resid = bf16 xbuf, out = f32 d_out, Ktot=256.
__global__ __launch_bounds__(512) void gemm_ln_kernel(
    const u16* __restrict__ A, const u16* __restrict__ BT, const float* __restrict__ bias,
    const float* __restrict__ residf, const u16* __restrict__ residb,
    const float* __restrict__ gam, const float* __restrict__ bet,
    u16* __restrict__ outb, float* __restrict__ outf, int Ktot, int mode)
{
  __shared__ u16 lA[2][512];            // [kq 0..3][16 rows][8]
  __shared__ u16 lB[2][8192];           // [kq 0..3][256 cols][8]
  __shared__ float lsum[8][16];
  __shared__ float lsq[8][16];
  const int t = threadIdx.x;
  const int w = t >> 6, lane = t & 63, quad = lane >> 4, lc = lane & 15;
  const int bb = blockIdx.x;
  const u16* A0 = A + bb * 16 * Ktot;

  const f32x4 fz = {0.f, 0.f, 0.f, 0.f};
  f32x4 acc0 = fz, acc1 = fz;           // wave w owns cols [w*32, w*32+32)

#define GLN_STAGE(ck, b) do {                                            \
    const int ko_ = (ck) * 32;                                           \
    if (w == 0)                                                          \
      gl_lds16(A0 + (lane & 15) * Ktot + ko_ + (lane >> 4) * 8,          \
               &lA[b][0]);                                               \
    _Pragma("unroll")                                                    \
    for (int s_ = 0; s_ < 2; ++s_) {                                     \
      const int i_ = w * 2 + s_;                                         \
      const int kq_ = i_ >> 2, rg_ = i_ & 3;                             \
      gl_lds16(BT + (rg_ * 64 + lane) * Ktot + ko_ + kq_ * 8,            \
               &lB[b][kq_ * 2048 + rg_ * 512]);                          \
    }                                                                    \
  } while (0)

  const int nck = Ktot >> 5;
  GLN_STAGE(0, 0);
  for (int ck = 0; ck < nck; ++ck) {
    const int cur = ck & 1;
    if (ck < nck - 1) {
      GLN_STAGE(ck + 1, cur ^ 1);
      if (w == 0) asm volatile("s_waitcnt vmcnt(3)" ::: "memory");
      else        asm volatile("s_waitcnt vmcnt(2)" ::: "memory");
    } else {
      asm volatile("s_waitcnt vmcnt(0)" ::: "memory");
    }
    __builtin_amdgcn_s_barrier();
    asm volatile("" ::: "memory");
    const bf16x8 af = *(const bf16x8*)&lA[cur][quad * 128 + lc * 8];
    const bf16x8 b0 = *(const bf16x8*)&lB[cur][quad * 2048 + (w * 32 + lc) * 8];
    const bf16x8 b1 = *(const bf16x8*)&lB[cur][quad * 2048 + (w * 32 + 16 + lc) * 8];
    acc0 = __builtin_amdgcn_mfma_f32_16x16x32_bf16(af, b0, acc0, 0, 0, 0);
    acc1 = __builtin_amdgcn_mfma_f32_16x16x32_bf16(af, b1, acc1, 0, 0, 0);
    asm volatile("s_waitcnt lgkmcnt(0)" ::: "memory");
    __builtin_amdgcn_s_barrier();
  }
#undef GLN_STAGE

  // epilogue: + bias + residual, then full-row LN (block owns all 256 cols)
  const int col0 = w * 32 + lc, col1 = w * 32 + 16 + lc;
  const float bi0 = bias[col0], bi1 = bias[col1];
#pragma unroll
  for (int r = 0; r < 4; ++r) {
    const int row = bb * 16 + quad * 4 + r;
    if (mode == 0) {
      acc0[r] += bi0 + residf[row * 256 + col0];
      acc1[r] += bi1 + residf[row * 256 + col1];
    } else {
      acc0[r] += bi0 + bf2f(residb[row * 256 + col0]);
      acc1[r] += bi1 + bf2f(residb[row * 256 + col1]);
    }
  }
  // per-wave row partials over its 32 cols -> LDS
#pragma unroll
  for (int r = 0; r < 4; ++r) {
    float s = acc0[r] + acc1[r];
    float q = acc0[r] * acc0[r] + acc1[r] * acc1[r];
    s += __shfl_xor(s, 1); s += __shfl_xor(s, 2);
    s += __shfl_xor(s, 4); s += __shfl_xor(s, 8);
    q += __shfl_xor(q, 1); q += __shfl_xor(q, 2);
    q += __shfl_xor(q, 4); q += __shfl_xor(q, 8);
    if (lc == 0) {
      const int rr = quad * 4 + r;
      lsum[w][rr] = s; lsq[w][rr] = q;
    }
  }
  __syncthreads();
#pragma unroll
  for (int r = 0; r < 4; ++r) {
    const int rr = quad * 4 + r;
    float s = 0.f, q = 0.f;
#pragma unroll
    for (int ww = 0; ww < 8; ++ww) { s += lsum[ww][rr]; q += lsq[ww][rr]; }
    const float mean = s * (1.0f / 256.0f);
    const float rs = rsqrtf(q * (1.0f / 256.0f) - mean * mean + 1e-5f);
    const int row = bb * 16 + rr;
    const float v0 = (acc0[r] - mean) * rs * gam[col0] + bet[col0];
    const float v1 = (acc1[r] - mean) * rs * gam[col1] + bet[col1];
    if (mode == 0) {
      outb[row * 256 + col0] = f2bf(v0);
      outb[row * 256 + col1] = f2bf(v1);
    } else {
      outf[row * 256 + col0] = v0;
      outf[row * 256 + col1] = v1;
    }
  }
}

extern "C" void kernel_launch(void* const* d_in, const int* in_sizes, int n_in,
                              void* d_out, int out_size, void* d_ws, size_t ws_size,
                              hipStream_t stream) {
  (void)in_sizes; (void)n_in; (void)out_size; (void)ws_size;
  const float* query = (const float*)d_in[0];
  const float* key   = (const float*)d_in[1];
  const float* value = (const float*)d_in[2];
  const float* Wq  = (const float*)d_in[3];
  const float* bq  = (const float*)d_in[4];
  const float* Wk  = (const float*)d_in[5];
  const float* bk  = (const float*)d_in[6];
  const float* Wv  = (const float*)d_in[7];
  const float* bv  = (const float*)d_in[8];
  const float* Wo  = (const float*)d_in[9];
  const float* bo  = (const float*)d_in[10];
  const float* g1  = (const float*)d_in[11];
  const float* b1  = (const float*)d_in[12];
  const float* Wff = (const float*)d_in[13];
  const float* bff = (const float*)d_in[14];
  const float* g2  = (const float*)d_in[15];
  const float* b2  = (const float*)d_in[16];

  u16* ws  = (u16*)d_ws;
  u16* WT  = ws;                      // [0, 2162688)
  u16* qb  = ws + 2162688;            // 2,097,152 each (8192x256 bf16)
  u16* kb  = ws + 4259840;
  u16* vb  = ws + 6356992;
  u16* Pq  = ws + 8454144;            // 16,777,216 each (8192x2048 bf16)
  u16* Pk  = ws + 25231360;
  u16* VT  = ws + 42008576;           // 512 groups x [d=256][q'=128]
  u16* Obuf = ws + 58785792;          // 33,554,432 B (linear gathered 8192x2048 bf16)
  u16* Pv  = Obuf;                    // same region (dead before attn writes O)
  u16* xbuf = ws + 49872896;          // 2,097,152 u16 within VT region (dead after attn)

  convert_kernel<<<dim3(2048, 3), 256, 0, stream>>>(query, key, value, qb, kb, vb);
  transpose_kernel<<<dim3(2048, 5), 256, 0, stream>>>(Wq, Wk, Wv, Wo, Wff, WT);
  proj_kernel<<<dim3(16, 64, 3), 256, 0, stream>>>(qb, kb, vb, WT, bq, bk, bv, Pq, Pk, Pv);
  vtrans_kernel<<<dim3(8, 512), 256, 0, stream>>>(Pv, VT);
  // Dedup'd attention: 512 distinct units, linear gathered output.
  attn_kernel<<<dim3(64, 8), 512, 0, stream>>>(Pq, Pk, VT, Obuf);
  // Wo GEMM + bias + value-resid + LN1 fused (16-row tiles, 512 blocks) -> bf16 xbuf.
  gemm_ln_kernel<<<512, 512, 0, stream>>>(Obuf, WT + 1572864, bo, value, nullptr,
                                          g1, b1, xbuf, nullptr, 2048, 0);
  // FF GEMM + bias + xbuf-resid + LN2 fused -> f32 d_out.
  gemm_ln_kernel<<<512, 512, 0, stream>>>(xbuf, WT + 2097152, bff, nullptr, xbuf,
                                          g2, b2, nullptr, (float*)d_out, 256, 1);
}

// Round 10
// 256.448 us; speedup vs baseline: 1.1882x; 1.1882x over previous
//
#include <hip/hip_runtime.h>
#include <cstdint>

typedef unsigned short u16;
typedef __attribute__((ext_vector_type(8))) short bf16x8;
typedef __attribute__((ext_vector_type(4))) float f32x4;
typedef __attribute__((ext_vector_type(4))) unsigned short u16x4;

#define AS_G __attribute__((address_space(1)))
#define AS_L __attribute__((address_space(3)))

__device__ __forceinline__ void gl_lds16(const u16* g, u16* l) {
  // async global->LDS, 16B/lane; LDS dest = wave-uniform base + lane*16
  __builtin_amdgcn_global_load_lds((const AS_G unsigned int*)g, (AS_L unsigned int*)l, 16, 0, 0);
}
__device__ __forceinline__ float bf2f(u16 u) {
  union { unsigned int i; float f; } v; v.i = ((unsigned int)u) << 16; return v.f;
}
__device__ __forceinline__ u16 f2bf(float f) {
  union { float f; unsigned int i; } v; v.f = f;
  unsigned int x = v.i;
  return (u16)((x + 0x7fffu + ((x >> 16) & 1u)) >> 16);  // RNE
}

// ---------------- merged input convert + weight pre-transpose ----------------
// blockIdx.y < 3: fp32->bf16 convert of q/k/v. blockIdx.y >= 3: weight
// transpose (fp32 src -> bf16 dst). One dispatch instead of two.
__global__ __launch_bounds__(256) void prep_kernel(
    const float* __restrict__ q, const float* __restrict__ k, const float* __restrict__ v,
    u16* __restrict__ qb, u16* __restrict__ kb, u16* __restrict__ vb,
    const float* __restrict__ s0, const float* __restrict__ s1, const float* __restrict__ s2,
    const float* __restrict__ s3, const float* __restrict__ s4, u16* __restrict__ wdst)
{
  const int id = blockIdx.y;
  if (id < 3) {
    const float* s = (id == 0) ? q : (id == 1) ? k : v;
    u16* d = (id == 0) ? qb : (id == 1) ? kb : vb;
    const int o = (blockIdx.x * 256 + threadIdx.x) * 4;
    const f32x4 x = *(const f32x4*)(s + o);
    u16x4 y;
#pragma unroll
    for (int i = 0; i < 4; ++i) y[i] = f2bf(x[i]);
    *(u16x4*)(d + o) = y;
  } else {
    const float* src; u16* dst; int rb, total;
    switch (id - 3) {
      case 0:  src = s0; dst = wdst;           rb = 8;  total = 524288; break;
      case 1:  src = s1; dst = wdst + 524288;  rb = 8;  total = 524288; break;
      case 2:  src = s2; dst = wdst + 1048576; rb = 8;  total = 524288; break;
      case 3:  src = s3; dst = wdst + 1572864; rb = 11; total = 524288; break;
      default: src = s4; dst = wdst + 2097152; rb = 8;  total = 65536;  break;
    }
    const int o = blockIdx.x * 256 + threadIdx.x;
    if (o >= total) return;
    const int C_ = total >> rb;
    const int c = o >> rb, r = o & ((1 << rb) - 1);
    dst[o] = f2bf(src[r * C_ + c]);
  }
}

// ---------------- QKV projection on the UNGATHERED 8192 rows ----------------
// R2 structure (best measured: 64.4 us).
__global__ __launch_bounds__(256) void proj_kernel(
    const u16* __restrict__ qb, const u16* __restrict__ kb, const u16* __restrict__ vb,
    const u16* __restrict__ wts, const float* __restrict__ bq, const float* __restrict__ bk,
    const float* __restrict__ bv, u16* __restrict__ Pq, u16* __restrict__ Pk,
    u16* __restrict__ Pv)
{
  __shared__ u16 lds[16384];            // buf b at [b*8192): A [0,4096)+B [4096,8192); epilogue: 64x136 per half
  const int t = threadIdx.x;
  const int w = t >> 6, lane = t & 63, quad = lane >> 4, lc = lane & 15;
  const int wy = w >> 1, wx = w & 1;
  // swizzle: same-by blocks (sharing the A slab) are XCD-local.
  const int flat = blockIdx.x + (blockIdx.y << 4);   // 0..1023
  const int tn = flat >> 6, by = flat & 63, z = blockIdx.z;
  const u16* A0 = ((z == 0) ? qb : (z == 1) ? kb : vb) + by * 32768;   // 128 rows x 256
  const u16* BT = wts + z * 524288 + tn * 128 * 256;

  const f32x4 fz = {0.f, 0.f, 0.f, 0.f};
  f32x4 acc[4][4];
#pragma unroll
  for (int i = 0; i < 4; ++i)
#pragma unroll
    for (int j = 0; j < 4; ++j) acc[i][j] = fz;

#define PROJ_STAGE(ck, b) do {                                         \
    const int ko_ = (ck) * 32 + w * 8;                                 \
    u16* Lb_ = &lds[(b) * 8192];                                       \
    gl_lds16(A0 + lane * 256 + ko_,        Lb_ + w * 1024);            \
    gl_lds16(A0 + (64 + lane) * 256 + ko_, Lb_ + w * 1024 + 512);      \
    gl_lds16(BT + lane * 256 + ko_,        Lb_ + 4096 + w * 1024);     \
    gl_lds16(BT + (64 + lane) * 256 + ko_, Lb_ + 4096 + w * 1024 + 512); \
  } while (0)

  PROJ_STAGE(0, 0);
#pragma unroll
  for (int ck = 0; ck < 8; ++ck) {
    const int cur = ck & 1;
    if (ck < 7) {
      PROJ_STAGE(ck + 1, cur ^ 1);
      asm volatile("s_waitcnt vmcnt(4)" ::: "memory");   // own chunk-ck loads landed; prefetch stays in flight
    } else {
      asm volatile("s_waitcnt vmcnt(0)" ::: "memory");
    }
    __builtin_amdgcn_s_barrier();                        // all waves' chunk-ck loads landed
    asm volatile("" ::: "memory");
    const u16* Ab = &lds[cur * 8192];
    const u16* Bb = &lds[cur * 8192 + 4096];
    bf16x8 af[4], bfg[4];
#pragma unroll
    for (int mi = 0; mi < 4; ++mi)
      af[mi] = *(const bf16x8*)&Ab[quad * 1024 + (wy * 64 + mi * 16 + lc) * 8];
#pragma unroll
    for (int ni = 0; ni < 4; ++ni)
      bfg[ni] = *(const bf16x8*)&Bb[quad * 1024 + (wx * 64 + ni * 16 + lc) * 8];
#pragma unroll
    for (int mi = 0; mi < 4; ++mi)
#pragma unroll
      for (int ni = 0; ni < 4; ++ni)
        acc[mi][ni] = __builtin_amdgcn_mfma_f32_16x16x32_bf16(af[mi], bfg[ni], acc[mi][ni], 0, 0, 0);
    asm volatile("s_waitcnt lgkmcnt(0)" ::: "memory");   // all ds_reads of buf[cur] done
    __builtin_amdgcn_s_barrier();                        // safe to overwrite buf[cur] next iter
  }
#undef PROJ_STAGE

  const float* bias = (z == 0) ? bq : (z == 1) ? bk : bv;
  u16* P = ((z == 0) ? Pq : (z == 1) ? Pk : Pv) + by * 262144;

  // Two 64-row epilogue passes; each uses only 64x136 u16 = 17408 B of LDS.
#pragma unroll
  for (int half = 0; half < 2; ++half) {
    __syncthreads();                     // prev pass reads / K-loop staging done
    if (wy == half) {
#pragma unroll
      for (int mi = 0; mi < 4; ++mi)
#pragma unroll
        for (int ni = 0; ni < 4; ++ni) {
          const int col = wx * 64 + ni * 16 + lc;
          const float bi = bias[tn * 128 + col];
#pragma unroll
          for (int r = 0; r < 4; ++r) {
            const int row = mi * 16 + quad * 4 + r;
            lds[row * 136 + col] = f2bf(acc[mi][ni][r] + bi);
          }
        }
    }
    __syncthreads();
#pragma unroll
    for (int p = 0; p < 4; ++p) {        // 256B-contiguous row segments, 16B/lane
      const int e = p * 2048 + t * 8;
      const int row = e >> 7, col0 = e & 127;
      *(bf16x8*)(P + (half * 64 + row) * 2048 + tn * 128 + col0) =
          *(const bf16x8*)&lds[row * 136 + col0];
    }
  }
}

// ---------------- Pv group-slab transpose (coalesced both sides) ----------------
__global__ __launch_bounds__(256) void vtrans_kernel(
    const u16* __restrict__ Pv, u16* __restrict__ VT)
{
  __shared__ u16 lT[4096];
  const int t = threadIdx.x;
  const int tile = blockIdx.x;          // 0..7
  const int g = blockIdx.y;             // 0..511
  const int q0 = (tile & 1) * 64, d0 = (tile >> 1) * 64;
  const u16* src = Pv + g * 32768;      // [q'=128][d=256]
  u16* dst = VT + g * 32768;            // [d=256][q'=128]
#pragma unroll
  for (int it = 0; it < 2; ++it) {
    const int e = it * 2048 + t * 8;
    const int lq = e >> 6, ld0 = e & 63;
    const bf16x8 v = *(const bf16x8*)(src + (q0 + lq) * 256 + d0 + ld0);
    const int kb = ((ld0 >> 3) + lq + (lq >> 3)) & 7;
    *(bf16x8*)&lT[lq * 64 + kb * 8] = v;
  }
  __syncthreads();
#pragma unroll
  for (int it = 0; it < 2; ++it) {
    const int e = it * 2048 + t * 8;
    const int ld = e >> 6, lq0 = e & 63;
    bf16x8 v;
#pragma unroll
    for (int i = 0; i < 8; ++i) {
      const int lq = lq0 + i;
      const int kb = ((ld >> 3) + lq + (lq >> 3)) & 7;
      v[i] = (short)lT[lq * 64 + kb * 8 + (ld & 7)];
    }
    *(bf16x8*)(dst + (d0 + ld) * 128 + q0 + lq0) = v;
  }
}

// ---------------- attention per DISTINCT unit (dedup'd, R7) ----------------
__global__ __launch_bounds__(512) void attn_kernel(
    const u16* __restrict__ Pq, const u16* __restrict__ Pk,
    const u16* __restrict__ VT, u16* __restrict__ Obuf)
{
  __shared__ u16 lKV[16384];
  __shared__ u16 lP[16384];
  const int t = threadIdx.x;
  const int w = t >> 6, lane = t & 63, quad = lane >> 4, lc = lane & 15;
  const int M = blockIdx.x, b = blockIdx.y;
  const int m0 = w * 16;
  const int r0 = b * 1024 + M * 16;
  const u16* Qb = Pq + r0 * 2048;
  const u16* Kb = Pk + r0 * 2048;
  const u16* Vb = VT + (b * 64 + M) * 32768;
  const f32x4 fz = {0.f, 0.f, 0.f, 0.f};

  bf16x8 aq[8];
#pragma unroll
  for (int kc = 0; kc < 8; ++kc)
    aq[kc] = *(const bf16x8*)(Qb + (m0 + lc) * 256 + kc * 32 + quad * 8);

  f32x4 s[8];
  for (int hk = 0; hk < 2; ++hk) {
    __syncthreads();
#pragma unroll
    for (int jj = 0; jj < 4; ++jj)
      gl_lds16(Kb + (hk * 64 + lane) * 256 + w * 32 + jj * 8, &lKV[w * 2048 + jj * 512]);
    __syncthreads();
#pragma unroll
    for (int ntl = 0; ntl < 4; ++ntl) {
      const int nt = hk * 4 + ntl;
      s[nt] = fz;
#pragma unroll
      for (int kc = 0; kc < 8; ++kc) {
        const bf16x8 bfr = *(const bf16x8*)&lKV[kc * 2048 + quad * 512 + (ntl * 16 + lc) * 8];
        s[nt] = __builtin_amdgcn_mfma_f32_16x16x32_bf16(aq[kc], bfr, s[nt], 0, 0, 0);
      }
    }
  }

  const float scale = 0.0625f;
#pragma unroll
  for (int r = 0; r < 4; ++r) {
    float mx = -3.0e38f;
#pragma unroll
    for (int nt = 0; nt < 8; ++nt) mx = fmaxf(mx, s[nt][r]);
    mx = fmaxf(mx, __shfl_xor(mx, 1)); mx = fmaxf(mx, __shfl_xor(mx, 2));
    mx = fmaxf(mx, __shfl_xor(mx, 4)); mx = fmaxf(mx, __shfl_xor(mx, 8));
    mx *= scale;
    float sm = 0.0f;
#pragma unroll
    for (int nt = 0; nt < 8; ++nt) {
      const float e = __expf(s[nt][r] * scale - mx);
      s[nt][r] = e; sm += e;
    }
    sm += __shfl_xor(sm, 1); sm += __shfl_xor(sm, 2);
    sm += __shfl_xor(sm, 4); sm += __shfl_xor(sm, 8);
    const float inv = 1.0f / sm;
    const int q = m0 + quad * 4 + r;
#pragma unroll
    for (int nt = 0; nt < 8; ++nt) {
      const int k = nt * 16 + lc;
      lP[(k >> 5) * 4096 + ((k >> 3) & 3) * 1024 + q * 8 + (k & 7)] = f2bf(s[nt][r] * inv);
    }
  }
  __syncthreads();

  bf16x8 ap[4];
#pragma unroll
  for (int kc2 = 0; kc2 < 4; ++kc2)
    ap[kc2] = *(const bf16x8*)&lP[kc2 * 4096 + quad * 1024 + (m0 + lc) * 8];

  f32x4 o[16];
#pragma unroll
  for (int nt = 0; nt < 16; ++nt) o[nt] = fz;

  for (int hk = 0; hk < 2; ++hk) {
    if (hk) __syncthreads();
#pragma unroll
    for (int jj = 0; jj < 4; ++jj) {
      const int i = w * 4 + jj;
      const int kc2l = i >> 4, cb = (i >> 2) & 3, db = (i & 3) * 64;
      gl_lds16(Vb + (db + lane) * 128 + (hk * 2 + kc2l) * 32 + cb * 8,
               &lKV[kc2l * 8192 + cb * 2048 + db * 8]);
    }
    __syncthreads();
#pragma unroll
    for (int nt = 0; nt < 16; ++nt)
#pragma unroll
      for (int kc2l = 0; kc2l < 2; ++kc2l) {
        const bf16x8 bfr = *(const bf16x8*)&lKV[kc2l * 8192 + quad * 2048 + (nt * 16 + lc) * 8];
        o[nt] = __builtin_amdgcn_mfma_f32_16x16x32_bf16(ap[hk * 2 + kc2l], bfr, o[nt], 0, 0, 0);
      }
  }

  u16* Ob = Obuf + r0 * 2048;           // linear gathered output rows [16M,16M+16)
#pragma unroll
  for (int nt = 0; nt < 16; ++nt)
#pragma unroll
    for (int r = 0; r < 4; ++r) {
      const int q = m0 + quad * 4 + r;
      Ob[q * 256 + nt * 16 + lc] = f2bf(o[nt][r]);
    }
}

// ---------------- Wo GEMM on the linear gathered rows (M=8192), split-K=4 ----------------
// R7 measured-good form (the R8/R9 fused-LN full-N variants were latency-bound:
// MfmaUtil 4%, 75-82 us; narrow-N + split-K is required to bury chunk latency).
__global__ __launch_bounds__(256) void gemm_wo_kernel(
    const u16* __restrict__ A, const u16* __restrict__ BT, float* __restrict__ out)
{
  __shared__ u16 lA[2][2048];           // [ks=4][64 rows][8]
  __shared__ u16 lB[2][8192];           // [ks=4][256 rows][8]
  const int t = threadIdx.x;
  const int w = t >> 6, lane = t & 63, quad = lane >> 4, lc = lane & 15;
  const int bb = blockIdx.x, kz = blockIdx.z;
  const int k0 = kz * 512;              // kslice = 2048/4
  const u16* Arow = A + (bb * 64 + lane) * 2048 + k0;
  const u16* BT0 = BT + k0;

  const f32x4 fz = {0.f, 0.f, 0.f, 0.f};
  f32x4 acc[4][4];
#pragma unroll
  for (int i = 0; i < 4; ++i)
#pragma unroll
    for (int jj = 0; jj < 4; ++jj) acc[i][jj] = fz;

#define GWO_STAGE(ck, b) do {                                          \
    const int ko_ = (ck) * 32 + w * 8;                                 \
    gl_lds16(Arow + ko_, &lA[b][w * 512]);                             \
    _Pragma("unroll")                                                  \
    for (int sg_ = 0; sg_ < 4; ++sg_)                                  \
      gl_lds16(BT0 + (sg_ * 64 + lane) * 2048 + ko_,                   \
               &lB[b][w * 2048 + sg_ * 512]);                          \
  } while (0)

  GWO_STAGE(0, 0);
  for (int ck = 0; ck < 16; ++ck) {
    const int cur = ck & 1;
    if (ck < 15) {
      GWO_STAGE(ck + 1, cur ^ 1);
      asm volatile("s_waitcnt vmcnt(5)" ::: "memory");
    } else {
      asm volatile("s_waitcnt vmcnt(0)" ::: "memory");
    }
    __builtin_amdgcn_s_barrier();
    asm volatile("" ::: "memory");
    bf16x8 af[4], bfg[4];
#pragma unroll
    for (int mi = 0; mi < 4; ++mi)
      af[mi] = *(const bf16x8*)&lA[cur][quad * 512 + (mi * 16 + lc) * 8];
#pragma unroll
    for (int ni = 0; ni < 4; ++ni) {
      const int cl = w * 64 + ni * 16 + lc;
      bfg[ni] = *(const bf16x8*)&lB[cur][quad * 2048 + cl * 8];
    }
#pragma unroll
    for (int mi = 0; mi < 4; ++mi)
#pragma unroll
      for (int ni = 0; ni < 4; ++ni)
        acc[mi][ni] = __builtin_amdgcn_mfma_f32_16x16x32_bf16(af[mi], bfg[ni], acc[mi][ni], 0, 0, 0);
    asm volatile("s_waitcnt lgkmcnt(0)" ::: "memory");
    __builtin_amdgcn_s_barrier();
  }
#undef GWO_STAGE

  float* O = out + kz * 2097152 + bb * 64 * 256;
#pragma unroll
  for (int mi = 0; mi < 4; ++mi)
#pragma unroll
    for (int ni = 0; ni < 4; ++ni) {
      const int cg = w * 64 + ni * 16 + lc;
#pragma unroll
      for (int r = 0; r < 4; ++r)
        O[(mi * 16 + quad * 4 + r) * 256 + cg] = acc[mi][ni][r];
    }
}

// ---------------- FF GEMM (64x128 tile, K=256, fused bias+resid epilogue) ----------------
__global__ __launch_bounds__(256) void gemm_ff_kernel(
    const u16* __restrict__ A, const u16* __restrict__ BT, const float* __restrict__ bias,
    const u16* __restrict__ residb, float* __restrict__ out)
{
  __shared__ u16 lA[2][2048];
  __shared__ u16 lB[2][4096];
  const int t = threadIdx.x;
  const int w = t >> 6, lane = t & 63, quad = lane >> 4, lc = lane & 15;
  const int tn = blockIdx.x, bb = blockIdx.y;
  const u16* A0 = A + bb * 64 * 256;
  const u16* BT0 = BT + tn * 128 * 256;

  const f32x4 fz = {0.f, 0.f, 0.f, 0.f};
  f32x4 acc[4][2];
#pragma unroll
  for (int i = 0; i < 4; ++i) { acc[i][0] = fz; acc[i][1] = fz; }

#define GFF_STAGE(ck, b) do {                                          \
    const int ko_ = (ck) * 32 + w * 8;                                 \
    gl_lds16(A0 + lane * 256 + ko_,        &lA[b][w * 512]);           \
    gl_lds16(BT0 + lane * 256 + ko_,       &lB[b][w * 1024]);          \
    gl_lds16(BT0 + (64 + lane) * 256 + ko_, &lB[b][w * 1024 + 512]);   \
  } while (0)

  GFF_STAGE(0, 0);
  for (int ck = 0; ck < 8; ++ck) {
    const int cur = ck & 1;
    if (ck < 7) {
      GFF_STAGE(ck + 1, cur ^ 1);
      asm volatile("s_waitcnt vmcnt(3)" ::: "memory");
    } else {
      asm volatile("s_waitcnt vmcnt(0)" ::: "memory");
    }
    __builtin_amdgcn_s_barrier();
    asm volatile("" ::: "memory");
    bf16x8 af[4], bfg[2];
#pragma unroll
    for (int mi = 0; mi < 4; ++mi)
      af[mi] = *(const bf16x8*)&lA[cur][quad * 512 + (mi * 16 + lc) * 8];
#pragma unroll
    for (int ni = 0; ni < 2; ++ni) {
      const int cl = w * 32 + ni * 16 + lc;
      bfg[ni] = *(const bf16x8*)&lB[cur][quad * 1024 + (cl >> 6) * 512 + (cl & 63) * 8];
    }
#pragma unroll
    for (int mi = 0; mi < 4; ++mi)
#pragma unroll
      for (int ni = 0; ni < 2; ++ni)
        acc[mi][ni] = __builtin_amdgcn_mfma_f32_16x16x32_bf16(af[mi], bfg[ni], acc[mi][ni], 0, 0, 0);
    asm volatile("s_waitcnt lgkmcnt(0)" ::: "memory");
    __builtin_amdgcn_s_barrier();
  }
#undef GFF_STAGE

#pragma unroll
  for (int mi = 0; mi < 4; ++mi)
#pragma unroll
    for (int ni = 0; ni < 2; ++ni) {
      const int cg = tn * 128 + w * 32 + ni * 16 + lc;
      const float bi = bias[cg];
#pragma unroll
      for (int r = 0; r < 4; ++r) {
        const int rl = mi * 16 + quad * 4 + r;
        const float res = bf2f(residb[(bb * 64 + rl) * 256 + cg]);
        out[(bb * 64 + rl) * 256 + cg] = acc[mi][ni][r] + bi + res;
      }
    }
}

// ---------------- fused split-K reduce + bias + value-resid + LN1 -> bf16 ----------------
__global__ __launch_bounds__(256) void reduce_ln_kernel(
    const float* __restrict__ part, const float* __restrict__ bias,
    const float* __restrict__ value, const float* __restrict__ gam,
    const float* __restrict__ bet, u16* __restrict__ dstb)
{
  const int t = threadIdx.x, w = t >> 6, lane = t & 63;
  const int row = blockIdx.x * 4 + w;
  const int e = row * 256 + lane * 4;
  const int col = lane * 4;
  f32x4 s = *(const f32x4*)(part + e);
#pragma unroll
  for (int p = 1; p < 4; ++p) {
    const f32x4 v = *(const f32x4*)(part + p * 2097152 + e);
#pragma unroll
    for (int i = 0; i < 4; ++i) s[i] += v[i];
  }
  const f32x4 bi = *(const f32x4*)(bias + col);
  const f32x4 rv = *(const f32x4*)(value + e);
#pragma unroll
  for (int i = 0; i < 4; ++i) s[i] += bi[i] + rv[i];
  float sum = s[0] + s[1] + s[2] + s[3];
  float sq = s[0] * s[0] + s[1] * s[1] + s[2] * s[2] + s[3] * s[3];
#pragma unroll
  for (int m = 1; m < 64; m <<= 1) { sum += __shfl_xor(sum, m); sq += __shfl_xor(sq, m); }
  const float mean = sum * (1.0f / 256.0f);
  const float rs = rsqrtf(sq * (1.0f / 256.0f) - mean * mean + 1e-5f);
  const f32x4 g4 = *(const f32x4*)(gam + col);
  const f32x4 b4 = *(const f32x4*)(bet + col);
  u16x4 ob;
#pragma unroll
  for (int i = 0; i < 4; ++i) ob[i] = f2bf((s[i] - mean) * rs * g4[i] + b4[i]);
  *(u16x4*)(dstb + row * 256 + lane * 4) = ob;
}

// ---------------- final layernorm -> d_out ----------------
__global__ __launch_bounds__(256) void ln2_kernel(
    const float* __restrict__ src, const float* __restrict__ gam, const float* __restrict__ bet,
    float* __restrict__ dstf)
{
  const int t = threadIdx.x, w = t >> 6, lane = t & 63;
  const int row = blockIdx.x * 4 + w;
  const f32x4 v = *(const f32x4*)(src + row * 256 + lane * 4);
  float sum = v[0] + v[1] + v[2] + v[3];
  float sq = v[0] * v[0] + v[1] * v[1] + v[2] * v[2] + v[3] * v[3];
#pragma unroll
  for (int m = 1; m < 64; m <<= 1) { sum += __shfl_xor(sum, m); sq += __shfl_xor(sq, m); }
  const float mean = sum * (1.0f / 256.0f);
  const float rs = rsqrtf(sq * (1.0f / 256.0f) - mean * mean + 1e-5f);
  const f32x4 g4 = *(const f32x4*)(gam + lane * 4);
  const f32x4 b4 = *(const f32x4*)(bet + lane * 4);
  f32x4 o;
#pragma unroll
  for (int i = 0; i < 4; ++i)
    o[i] = (v[i] - mean) * rs * g4[i] + b4[i];
  *(f32x4*)(dstf + row * 256 + lane * 4) = o;
}

extern "C" void kernel_launch(void* const* d_in, const int* in_sizes, int n_in,
                              void* d_out, int out_size, void* d_ws, size_t ws_size,
                              hipStream_t stream) {
  (void)in_sizes; (void)n_in; (void)out_size; (void)ws_size;
  const float* query = (const float*)d_in[0];
  const float* key   = (const float*)d_in[1];
  const float* value = (const float*)d_in[2];
  const float* Wq  = (const float*)d_in[3];
  const float* bq  = (const float*)d_in[4];
  const float* Wk  = (const float*)d_in[5];
  const float* bk  = (const float*)d_in[6];
  const float* Wv  = (const float*)d_in[7];
  const float* bv  = (const float*)d_in[8];
  const float* Wo  = (const float*)d_in[9];
  const float* bo  = (const float*)d_in[10];
  const float* g1  = (const float*)d_in[11];
  const float* b1  = (const float*)d_in[12];
  const float* Wff = (const float*)d_in[13];
  const float* bff = (const float*)d_in[14];
  const float* g2  = (const float*)d_in[15];
  const float* b2  = (const float*)d_in[16];

  u16* ws  = (u16*)d_ws;
  u16* WT  = ws;                      // [0, 2162688)
  u16* qb  = ws + 2162688;            // 2,097,152 each (8192x256 bf16)
  u16* kb  = ws + 4259840;
  u16* vb  = ws + 6356992;
  u16* Pq  = ws + 8454144;            // 16,777,216 each (8192x2048 bf16)
  u16* Pk  = ws + 25231360;
  u16* VT  = ws + 42008576;           // 512 groups x [d=256][q'=128]
  u16* Obuf = ws + 58785792;          // 33,554,432 B (linear gathered 8192x2048 bf16)
  u16* Pv  = Obuf;                    // same region (dead before attn writes O)
  float* part = (float*)(ws + 8454144);   // 4 x 2,097,152 f32 over Pq+Pk (dead after attn)
  u16* xbuf   = ws + 49872896;            // 2,097,152 u16 within VT region (dead after attn)
  float* tmp2 = (float*)(ws + 42008576);  // 8,388,608 B over VT start; ends before xbuf. disjoint.

  prep_kernel<<<dim3(2048, 8), 256, 0, stream>>>(query, key, value, qb, kb, vb,
                                                 Wq, Wk, Wv, Wo, Wff, WT);
  proj_kernel<<<dim3(16, 64, 3), 256, 0, stream>>>(qb, kb, vb, WT, bq, bk, bv, Pq, Pk, Pv);
  vtrans_kernel<<<dim3(8, 512), 256, 0, stream>>>(Pv, VT);
  // Dedup'd attention: 512 distinct units, linear gathered output.
  attn_kernel<<<dim3(64, 8), 512, 0, stream>>>(Pq, Pk, VT, Obuf);
  // Wo GEMM on linear rows (M=8192), split-K=4 -> partials.
  gemm_wo_kernel<<<dim3(128, 1, 4), 256, 0, stream>>>(Obuf, WT + 1572864, part);
  reduce_ln_kernel<<<2048, 256, 0, stream>>>(part, bo, value, g1, b1, xbuf);
  gemm_ff_kernel<<<dim3(2, 128), 256, 0, stream>>>(xbuf, WT + 2097152, bff, xbuf, tmp2);
  ln2_kernel<<<2048, 256, 0, stream>>>(tmp2, g2, b2, (float*)d_out);
}

// Round 11
// 251.882 us; speedup vs baseline: 1.2097x; 1.0181x over previous
//
#include <hip/hip_runtime.h>
#include <cstdint>

typedef unsigned short u16;
typedef __attribute__((ext_vector_type(8))) short bf16x8;
typedef __attribute__((ext_vector_type(4))) float f32x4;
typedef __attribute__((ext_vector_type(4))) unsigned short u16x4;

#define AS_G __attribute__((address_space(1)))
#define AS_L __attribute__((address_space(3)))

__device__ __forceinline__ void gl_lds16(const u16* g, u16* l) {
  // async global->LDS, 16B/lane; LDS dest = wave-uniform base + lane*16
  __builtin_amdgcn_global_load_lds((const AS_G unsigned int*)g, (AS_L unsigned int*)l, 16, 0, 0);
}
__device__ __forceinline__ float bf2f(u16 u) {
  union { unsigned int i; float f; } v; v.i = ((unsigned int)u) << 16; return v.f;
}
__device__ __forceinline__ u16 f2bf(float f) {
  union { float f; unsigned int i; } v; v.f = f;
  unsigned int x = v.i;
  return (u16)((x + 0x7fffu + ((x >> 16) & 1u)) >> 16);  // RNE
}

// ---------------- merged input convert + weight pre-transpose ----------------
__global__ __launch_bounds__(256) void prep_kernel(
    const float* __restrict__ q, const float* __restrict__ k, const float* __restrict__ v,
    u16* __restrict__ qb, u16* __restrict__ kb, u16* __restrict__ vb,
    const float* __restrict__ s0, const float* __restrict__ s1, const float* __restrict__ s2,
    const float* __restrict__ s3, const float* __restrict__ s4, u16* __restrict__ wdst)
{
  const int id = blockIdx.y;
  if (id < 3) {
    const float* s = (id == 0) ? q : (id == 1) ? k : v;
    u16* d = (id == 0) ? qb : (id == 1) ? kb : vb;
    const int o = (blockIdx.x * 256 + threadIdx.x) * 4;
    const f32x4 x = *(const f32x4*)(s + o);
    u16x4 y;
#pragma unroll
    for (int i = 0; i < 4; ++i) y[i] = f2bf(x[i]);
    *(u16x4*)(d + o) = y;
  } else {
    const float* src; u16* dst; int rb, total;
    switch (id - 3) {
      case 0:  src = s0; dst = wdst;           rb = 8;  total = 524288; break;
      case 1:  src = s1; dst = wdst + 524288;  rb = 8;  total = 524288; break;
      case 2:  src = s2; dst = wdst + 1048576; rb = 8;  total = 524288; break;
      case 3:  src = s3; dst = wdst + 1572864; rb = 11; total = 524288; break;
      default: src = s4; dst = wdst + 2097152; rb = 8;  total = 65536;  break;
    }
    const int o = blockIdx.x * 256 + threadIdx.x;
    if (o >= total) return;
    const int C_ = total >> rb;
    const int c = o >> rb, r = o & ((1 << rb) - 1);
    dst[o] = f2bf(src[r * C_ + c]);
  }
}

// ---------------- QKV projection on the UNGATHERED 8192 rows ----------------
// R2 structure (best measured: 64.4 us).
__global__ __launch_bounds__(256) void proj_kernel(
    const u16* __restrict__ qb, const u16* __restrict__ kb, const u16* __restrict__ vb,
    const u16* __restrict__ wts, const float* __restrict__ bq, const float* __restrict__ bk,
    const float* __restrict__ bv, u16* __restrict__ Pq, u16* __restrict__ Pk,
    u16* __restrict__ Pv)
{
  __shared__ u16 lds[16384];            // buf b at [b*8192): A [0,4096)+B [4096,8192); epilogue: 64x136 per half
  const int t = threadIdx.x;
  const int w = t >> 6, lane = t & 63, quad = lane >> 4, lc = lane & 15;
  const int wy = w >> 1, wx = w & 1;
  // swizzle: same-by blocks (sharing the A slab) are XCD-local.
  const int flat = blockIdx.x + (blockIdx.y << 4);   // 0..1023
  const int tn = flat >> 6, by = flat & 63, z = blockIdx.z;
  const u16* A0 = ((z == 0) ? qb : (z == 1) ? kb : vb) + by * 32768;   // 128 rows x 256
  const u16* BT = wts + z * 524288 + tn * 128 * 256;

  const f32x4 fz = {0.f, 0.f, 0.f, 0.f};
  f32x4 acc[4][4];
#pragma unroll
  for (int i = 0; i < 4; ++i)
#pragma unroll
    for (int j = 0; j < 4; ++j) acc[i][j] = fz;

#define PROJ_STAGE(ck, b) do {                                         \
    const int ko_ = (ck) * 32 + w * 8;                                 \
    u16* Lb_ = &lds[(b) * 8192];                                       \
    gl_lds16(A0 + lane * 256 + ko_,        Lb_ + w * 1024);            \
    gl_lds16(A0 + (64 + lane) * 256 + ko_, Lb_ + w * 1024 + 512);      \
    gl_lds16(BT + lane * 256 + ko_,        Lb_ + 4096 + w * 1024);     \
    gl_lds16(BT + (64 + lane) * 256 + ko_, Lb_ + 4096 + w * 1024 + 512); \
  } while (0)

  PROJ_STAGE(0, 0);
#pragma unroll
  for (int ck = 0; ck < 8; ++ck) {
    const int cur = ck & 1;
    if (ck < 7) {
      PROJ_STAGE(ck + 1, cur ^ 1);
      asm volatile("s_waitcnt vmcnt(4)" ::: "memory");   // own chunk-ck loads landed; prefetch stays in flight
    } else {
      asm volatile("s_waitcnt vmcnt(0)" ::: "memory");
    }
    __builtin_amdgcn_s_barrier();                        // all waves' chunk-ck loads landed
    asm volatile("" ::: "memory");
    const u16* Ab = &lds[cur * 8192];
    const u16* Bb = &lds[cur * 8192 + 4096];
    bf16x8 af[4], bfg[4];
#pragma unroll
    for (int mi = 0; mi < 4; ++mi)
      af[mi] = *(const bf16x8*)&Ab[quad * 1024 + (wy * 64 + mi * 16 + lc) * 8];
#pragma unroll
    for (int ni = 0; ni < 4; ++ni)
      bfg[ni] = *(const bf16x8*)&Bb[quad * 1024 + (wx * 64 + ni * 16 + lc) * 8];
#pragma unroll
    for (int mi = 0; mi < 4; ++mi)
#pragma unroll
      for (int ni = 0; ni < 4; ++ni)
        acc[mi][ni] = __builtin_amdgcn_mfma_f32_16x16x32_bf16(af[mi], bfg[ni], acc[mi][ni], 0, 0, 0);
    asm volatile("s_waitcnt lgkmcnt(0)" ::: "memory");   // all ds_reads of buf[cur] done
    __builtin_amdgcn_s_barrier();                        // safe to overwrite buf[cur] next iter
  }
#undef PROJ_STAGE

  const float* bias = (z == 0) ? bq : (z == 1) ? bk : bv;
  u16* P = ((z == 0) ? Pq : (z == 1) ? Pk : Pv) + by * 262144;

  // Two 64-row epilogue passes; each uses only 64x136 u16 = 17408 B of LDS.
#pragma unroll
  for (int half = 0; half < 2; ++half) {
    __syncthreads();                     // prev pass reads / K-loop staging done
    if (wy == half) {
#pragma unroll
      for (int mi = 0; mi < 4; ++mi)
#pragma unroll
        for (int ni = 0; ni < 4; ++ni) {
          const int col = wx * 64 + ni * 16 + lc;
          const float bi = bias[tn * 128 + col];
#pragma unroll
          for (int r = 0; r < 4; ++r) {
            const int row = mi * 16 + quad * 4 + r;
            lds[row * 136 + col] = f2bf(acc[mi][ni][r] + bi);
          }
        }
    }
    __syncthreads();
#pragma unroll
    for (int p = 0; p < 4; ++p) {        // 256B-contiguous row segments, 16B/lane
      const int e = p * 2048 + t * 8;
      const int row = e >> 7, col0 = e & 127;
      *(bf16x8*)(P + (half * 64 + row) * 2048 + tn * 128 + col0) =
          *(const bf16x8*)&lds[row * 136 + col0];
    }
  }
}

// ---------------- Pv group-slab transpose (coalesced both sides) ----------------
__global__ __launch_bounds__(256) void vtrans_kernel(
    const u16* __restrict__ Pv, u16* __restrict__ VT)
{
  __shared__ u16 lT[4096];
  const int t = threadIdx.x;
  const int tile = blockIdx.x;          // 0..7
  const int g = blockIdx.y;             // 0..511
  const int q0 = (tile & 1) * 64, d0 = (tile >> 1) * 64;
  const u16* src = Pv + g * 32768;      // [q'=128][d=256]
  u16* dst = VT + g * 32768;            // [d=256][q'=128]
#pragma unroll
  for (int it = 0; it < 2; ++it) {
    const int e = it * 2048 + t * 8;
    const int lq = e >> 6, ld0 = e & 63;
    const bf16x8 v = *(const bf16x8*)(src + (q0 + lq) * 256 + d0 + ld0);
    const int kb = ((ld0 >> 3) + lq + (lq >> 3)) & 7;
    *(bf16x8*)&lT[lq * 64 + kb * 8] = v;
  }
  __syncthreads();
#pragma unroll
  for (int it = 0; it < 2; ++it) {
    const int e = it * 2048 + t * 8;
    const int ld = e >> 6, lq0 = e & 63;
    bf16x8 v;
#pragma unroll
    for (int i = 0; i < 8; ++i) {
      const int lq = lq0 + i;
      const int kb = ((ld >> 3) + lq + (lq >> 3)) & 7;
      v[i] = (short)lT[lq * 64 + kb * 8 + (ld & 7)];
    }
    *(bf16x8*)(dst + (d0 + ld) * 128 + q0 + lq0) = v;
  }
}

// ---------------- attention per DISTINCT unit (dedup'd) ----------------
// NEW (this round): ping-pong overlap schedule. bufA/bufB (the old lKV/lP)
// alternate roles so every stage is issued BEFORE the compute that hides it:
//   K0->A; [K1->B || QK0(A)]; QK1(B); bar frees B; [V0->B || softmax,P->A];
//   ap<-A; [V1->A || PV0(B)]; PV1(A).
// Buffer-liveness: a buffer is only overwritten after a barrier that every
// wave reaches having already consumed (MFMA-issued, lgkm-waited) its reads
// of that buffer; ap-reads and P-writes get explicit lgkmcnt(0) before their
// barriers. Barriers 8 -> 6; K1/V0/V1 latency hidden. Compute bodies,
// layouts, softmax and stores are identical to R10.
__global__ __launch_bounds__(512) void attn_kernel(
    const u16* __restrict__ Pq, const u16* __restrict__ Pk,
    const u16* __restrict__ VT, u16* __restrict__ Obuf)
{
  __shared__ u16 bufA[16384];
  __shared__ u16 bufB[16384];
  const int t = threadIdx.x;
  const int w = t >> 6, lane = t & 63, quad = lane >> 4, lc = lane & 15;
  const int M = blockIdx.x, b = blockIdx.y;
  const int m0 = w * 16;
  const int r0 = b * 1024 + M * 16;
  const u16* Qb = Pq + r0 * 2048;
  const u16* Kb = Pk + r0 * 2048;
  const u16* Vb = VT + (b * 64 + M) * 32768;
  const f32x4 fz = {0.f, 0.f, 0.f, 0.f};

  bf16x8 aq[8];
#pragma unroll
  for (int kc = 0; kc < 8; ++kc)
    aq[kc] = *(const bf16x8*)(Qb + (m0 + lc) * 256 + kc * 32 + quad * 8);

  // stage K0 (rows 0..63) -> bufA
#pragma unroll
  for (int jj = 0; jj < 4; ++jj)
    gl_lds16(Kb + lane * 256 + w * 32 + jj * 8, &bufA[w * 2048 + jj * 512]);
  asm volatile("s_waitcnt vmcnt(0)" ::: "memory");       // K0 (and aq) landed
  __builtin_amdgcn_s_barrier();
  asm volatile("" ::: "memory");

  f32x4 s[8];
  // phase 1: stage K1 (rows 64..127) -> bufB, compute QK0 from bufA
#pragma unroll
  for (int jj = 0; jj < 4; ++jj)
    gl_lds16(Kb + (64 + lane) * 256 + w * 32 + jj * 8, &bufB[w * 2048 + jj * 512]);
#pragma unroll
  for (int ntl = 0; ntl < 4; ++ntl) {
    s[ntl] = fz;
#pragma unroll
    for (int kc = 0; kc < 8; ++kc) {
      const bf16x8 bfr = *(const bf16x8*)&bufA[kc * 2048 + quad * 512 + (ntl * 16 + lc) * 8];
      s[ntl] = __builtin_amdgcn_mfma_f32_16x16x32_bf16(aq[kc], bfr, s[ntl], 0, 0, 0);
    }
  }
  asm volatile("s_waitcnt vmcnt(0)" ::: "memory");       // K1 landed
  __builtin_amdgcn_s_barrier();
  asm volatile("" ::: "memory");

  // phase 2: compute QK1 from bufB
#pragma unroll
  for (int ntl = 0; ntl < 4; ++ntl) {
    s[4 + ntl] = fz;
#pragma unroll
    for (int kc = 0; kc < 8; ++kc) {
      const bf16x8 bfr = *(const bf16x8*)&bufB[kc * 2048 + quad * 512 + (ntl * 16 + lc) * 8];
      s[4 + ntl] = __builtin_amdgcn_mfma_f32_16x16x32_bf16(aq[kc], bfr, s[4 + ntl], 0, 0, 0);
    }
  }
  __builtin_amdgcn_s_barrier();                          // all K1 reads consumed -> bufB free
  asm volatile("" ::: "memory");

  // stage V0 -> bufB (latency hides under softmax)
#pragma unroll
  for (int jj = 0; jj < 4; ++jj) {
    const int i = w * 4 + jj;
    const int kc2l = i >> 4, cb = (i >> 2) & 3, db = (i & 3) * 64;
    gl_lds16(Vb + (db + lane) * 128 + kc2l * 32 + cb * 8,
             &bufB[kc2l * 8192 + cb * 2048 + db * 8]);
  }

  // softmax; P-writes -> bufA (K0 dead since barrier after phase 1)
  const float scale = 0.0625f;
#pragma unroll
  for (int r = 0; r < 4; ++r) {
    float mx = -3.0e38f;
#pragma unroll
    for (int nt = 0; nt < 8; ++nt) mx = fmaxf(mx, s[nt][r]);
    mx = fmaxf(mx, __shfl_xor(mx, 1)); mx = fmaxf(mx, __shfl_xor(mx, 2));
    mx = fmaxf(mx, __shfl_xor(mx, 4)); mx = fmaxf(mx, __shfl_xor(mx, 8));
    mx *= scale;
    float sm = 0.0f;
#pragma unroll
    for (int nt = 0; nt < 8; ++nt) {
      const float e = __expf(s[nt][r] * scale - mx);
      s[nt][r] = e; sm += e;
    }
    sm += __shfl_xor(sm, 1); sm += __shfl_xor(sm, 2);
    sm += __shfl_xor(sm, 4); sm += __shfl_xor(sm, 8);
    const float inv = 1.0f / sm;
    const int q = m0 + quad * 4 + r;
#pragma unroll
    for (int nt = 0; nt < 8; ++nt) {
      const int k = nt * 16 + lc;
      bufA[(k >> 5) * 4096 + ((k >> 3) & 3) * 1024 + q * 8 + (k & 7)] = f2bf(s[nt][r] * inv);
    }
  }
  asm volatile("s_waitcnt lgkmcnt(0)" ::: "memory");     // own P ds_writes retired
  __builtin_amdgcn_s_barrier();                          // P visible to all
  asm volatile("" ::: "memory");

  // ap <- P from bufA
  bf16x8 ap[4];
#pragma unroll
  for (int kc2 = 0; kc2 < 4; ++kc2)
    ap[kc2] = *(const bf16x8*)&bufA[kc2 * 4096 + quad * 1024 + (m0 + lc) * 8];
  asm volatile("s_waitcnt vmcnt(0) lgkmcnt(0)" ::: "memory");  // V0 landed; ap in regs
  __builtin_amdgcn_s_barrier();                          // bufA free for V1; bufB(V0) ready
  asm volatile("" ::: "memory");

  f32x4 o[16];
#pragma unroll
  for (int nt = 0; nt < 16; ++nt) o[nt] = fz;

  // phase 4: stage V1 -> bufA, compute PV0 (ap[0..1] x bufB)
#pragma unroll
  for (int jj = 0; jj < 4; ++jj) {
    const int i = w * 4 + jj;
    const int kc2l = i >> 4, cb = (i >> 2) & 3, db = (i & 3) * 64;
    gl_lds16(Vb + (db + lane) * 128 + (2 + kc2l) * 32 + cb * 8,
             &bufA[kc2l * 8192 + cb * 2048 + db * 8]);
  }
#pragma unroll
  for (int nt = 0; nt < 16; ++nt)
#pragma unroll
    for (int kc2l = 0; kc2l < 2; ++kc2l) {
      const bf16x8 bfr = *(const bf16x8*)&bufB[kc2l * 8192 + quad * 2048 + (nt * 16 + lc) * 8];
      o[nt] = __builtin_amdgcn_mfma_f32_16x16x32_bf16(ap[kc2l], bfr, o[nt], 0, 0, 0);
    }
  asm volatile("s_waitcnt vmcnt(0)" ::: "memory");       // V1 landed
  __builtin_amdgcn_s_barrier();
  asm volatile("" ::: "memory");

  // phase 5: compute PV1 (ap[2..3] x bufA)
#pragma unroll
  for (int nt = 0; nt < 16; ++nt)
#pragma unroll
    for (int kc2l = 0; kc2l < 2; ++kc2l) {
      const bf16x8 bfr = *(const bf16x8*)&bufA[kc2l * 8192 + quad * 2048 + (nt * 16 + lc) * 8];
      o[nt] = __builtin_amdgcn_mfma_f32_16x16x32_bf16(ap[2 + kc2l], bfr, o[nt], 0, 0, 0);
    }

  u16* Ob = Obuf + r0 * 2048;           // linear gathered output rows [16M,16M+16)
#pragma unroll
  for (int nt = 0; nt < 16; ++nt)
#pragma unroll
    for (int r = 0; r < 4; ++r) {
      const int q = m0 + quad * 4 + r;
      Ob[q * 256 + nt * 16 + lc] = f2bf(o[nt][r]);
    }
}

// ---------------- Wo GEMM on the linear gathered rows (M=8192), split-K=4 ----------------
__global__ __launch_bounds__(256) void gemm_wo_kernel(
    const u16* __restrict__ A, const u16* __restrict__ BT, float* __restrict__ out)
{
  __shared__ u16 lA[2][2048];           // [ks=4][64 rows][8]
  __shared__ u16 lB[2][8192];           // [ks=4][256 rows][8]
  const int t = threadIdx.x;
  const int w = t >> 6, lane = t & 63, quad = lane >> 4, lc = lane & 15;
  const int bb = blockIdx.x, kz = blockIdx.z;
  const int k0 = kz * 512;              // kslice = 2048/4
  const u16* Arow = A + (bb * 64 + lane) * 2048 + k0;
  const u16* BT0 = BT + k0;

  const f32x4 fz = {0.f, 0.f, 0.f, 0.f};
  f32x4 acc[4][4];
#pragma unroll
  for (int i = 0; i < 4; ++i)
#pragma unroll
    for (int jj = 0; jj < 4; ++jj) acc[i][jj] = fz;

#define GWO_STAGE(ck, b) do {                                          \
    const int ko_ = (ck) * 32 + w * 8;                                 \
    gl_lds16(Arow + ko_, &lA[b][w * 512]);                             \
    _Pragma("unroll")                                                  \
    for (int sg_ = 0; sg_ < 4; ++sg_)                                  \
      gl_lds16(BT0 + (sg_ * 64 + lane) * 2048 + ko_,                   \
               &lB[b][w * 2048 + sg_ * 512]);                          \
  } while (0)

  GWO_STAGE(0, 0);
  for (int ck = 0; ck < 16; ++ck) {
    const int cur = ck & 1;
    if (ck < 15) {
      GWO_STAGE(ck + 1, cur ^ 1);
      asm volatile("s_waitcnt vmcnt(5)" ::: "memory");
    } else {
      asm volatile("s_waitcnt vmcnt(0)" ::: "memory");
    }
    __builtin_amdgcn_s_barrier();
    asm volatile("" ::: "memory");
    bf16x8 af[4], bfg[4];
#pragma unroll
    for (int mi = 0; mi < 4; ++mi)
      af[mi] = *(const bf16x8*)&lA[cur][quad * 512 + (mi * 16 + lc) * 8];
#pragma unroll
    for (int ni = 0; ni < 4; ++ni) {
      const int cl = w * 64 + ni * 16 + lc;
      bfg[ni] = *(const bf16x8*)&lB[cur][quad * 2048 + cl * 8];
    }
#pragma unroll
    for (int mi = 0; mi < 4; ++mi)
#pragma unroll
      for (int ni = 0; ni < 4; ++ni)
        acc[mi][ni] = __builtin_amdgcn_mfma_f32_16x16x32_bf16(af[mi], bfg[ni], acc[mi][ni], 0, 0, 0);
    asm volatile("s_waitcnt lgkmcnt(0)" ::: "memory");
    __builtin_amdgcn_s_barrier();
  }
#undef GWO_STAGE

  float* O = out + kz * 2097152 + bb * 64 * 256;
#pragma unroll
  for (int mi = 0; mi < 4; ++mi)
#pragma unroll
    for (int ni = 0; ni < 4; ++ni) {
      const int cg = w * 64 + ni * 16 + lc;
#pragma unroll
      for (int r = 0; r < 4; ++r)
        O[(mi * 16 + quad * 4 + r) * 256 + cg] = acc[mi][ni][r];
    }
}

// ---------------- FF GEMM (64x128 tile, K=256, fused bias+resid epilogue) ----------------
__global__ __launch_bounds__(256) void gemm_ff_kernel(
    const u16* __restrict__ A, const u16* __restrict__ BT, const float* __restrict__ bias,
    const u16* __restrict__ residb, float* __restrict__ out)
{
  __shared__ u16 lA[2][2048];
  __shared__ u16 lB[2][4096];
  const int t = threadIdx.x;
  const int w = t >> 6, lane = t & 63, quad = lane >> 4, lc = lane & 15;
  const int tn = blockIdx.x, bb = blockIdx.y;
  const u16* A0 = A + bb * 64 * 256;
  const u16* BT0 = BT + tn * 128 * 256;

  const f32x4 fz = {0.f, 0.f, 0.f, 0.f};
  f32x4 acc[4][2];
#pragma unroll
  for (int i = 0; i < 4; ++i) { acc[i][0] = fz; acc[i][1] = fz; }

#define GFF_STAGE(ck, b) do {                                          \
    const int ko_ = (ck) * 32 + w * 8;                                 \
    gl_lds16(A0 + lane * 256 + ko_,        &lA[b][w * 512]);           \
    gl_lds16(BT0 + lane * 256 + ko_,       &lB[b][w * 1024]);          \
    gl_lds16(BT0 + (64 + lane) * 256 + ko_, &lB[b][w * 1024 + 512]);   \
  } while (0)

  GFF_STAGE(0, 0);
  for (int ck = 0; ck < 8; ++ck) {
    const int cur = ck & 1;
    if (ck < 7) {
      GFF_STAGE(ck + 1, cur ^ 1);
      asm volatile("s_waitcnt vmcnt(3)" ::: "memory");
    } else {
      asm volatile("s_waitcnt vmcnt(0)" ::: "memory");
    }
    __builtin_amdgcn_s_barrier();
    asm volatile("" ::: "memory");
    bf16x8 af[4], bfg[2];
#pragma unroll
    for (int mi = 0; mi < 4; ++mi)
      af[mi] = *(const bf16x8*)&lA[cur][quad * 512 + (mi * 16 + lc) * 8];
#pragma unroll
    for (int ni = 0; ni < 2; ++ni) {
      const int cl = w * 32 + ni * 16 + lc;
      bfg[ni] = *(const bf16x8*)&lB[cur][quad * 1024 + (cl >> 6) * 512 + (cl & 63) * 8];
    }
#pragma unroll
    for (int mi = 0; mi < 4; ++mi)
#pragma unroll
      for (int ni = 0; ni < 2; ++ni)
        acc[mi][ni] = __builtin_amdgcn_mfma_f32_16x16x32_bf16(af[mi], bfg[ni], acc[mi][ni], 0, 0, 0);
    asm volatile("s_waitcnt lgkmcnt(0)" ::: "memory");
    __builtin_amdgcn_s_barrier();
  }
#undef GFF_STAGE

#pragma unroll
  for (int mi = 0; mi < 4; ++mi)
#pragma unroll
    for (int ni = 0; ni < 2; ++ni) {
      const int cg = tn * 128 + w * 32 + ni * 16 + lc;
      const float bi = bias[cg];
#pragma unroll
      for (int r = 0; r < 4; ++r) {
        const int rl = mi * 16 + quad * 4 + r;
        const float res = bf2f(residb[(bb * 64 + rl) * 256 + cg]);
        out[(bb * 64 + rl) * 256 + cg] = acc[mi][ni][r] + bi + res;
      }
    }
}

// ---------------- fused split-K reduce + bias + value-resid + LN1 -> bf16 ----------------
__global__ __launch_bounds__(256) void reduce_ln_kernel(
    const float* __restrict__ part, const float* __restrict__ bias,
    const float* __restrict__ value, const float* __restrict__ gam,
    const float* __restrict__ bet, u16* __restrict__ dstb)
{
  const int t = threadIdx.x, w = t >> 6, lane = t & 63;
  const int row = blockIdx.x * 4 + w;
  const int e = row * 256 + lane * 4;
  const int col = lane * 4;
  f32x4 s = *(const f32x4*)(part + e);
#pragma unroll
  for (int p = 1; p < 4; ++p) {
    const f32x4 v = *(const f32x4*)(part + p * 2097152 + e);
#pragma unroll
    for (int i = 0; i < 4; ++i) s[i] += v[i];
  }
  const f32x4 bi = *(const f32x4*)(bias + col);
  const f32x4 rv = *(const f32x4*)(value + e);
#pragma unroll
  for (int i = 0; i < 4; ++i) s[i] += bi[i] + rv[i];
  float sum = s[0] + s[1] + s[2] + s[3];
  float sq = s[0] * s[0] + s[1] * s[1] + s[2] * s[2] + s[3] * s[3];
#pragma unroll
  for (int m = 1; m < 64; m <<= 1) { sum += __shfl_xor(sum, m); sq += __shfl_xor(sq, m); }
  const float mean = sum * (1.0f / 256.0f);
  const float rs = rsqrtf(sq * (1.0f / 256.0f) - mean * mean + 1e-5f);
  const f32x4 g4 = *(const f32x4*)(gam + col);
  const f32x4 b4 = *(const f32x4*)(bet + col);
  u16x4 ob;
#pragma unroll
  for (int i = 0; i < 4; ++i) ob[i] = f2bf((s[i] - mean) * rs * g4[i] + b4[i]);
  *(u16x4*)(dstb + row * 256 + lane * 4) = ob;
}

// ---------------- final layernorm -> d_out ----------------
__global__ __launch_bounds__(256) void ln2_kernel(
    const float* __restrict__ src, const float* __restrict__ gam, const float* __restrict__ bet,
    float* __restrict__ dstf)
{
  const int t = threadIdx.x, w = t >> 6, lane = t & 63;
  const int row = blockIdx.x * 4 + w;
  const f32x4 v = *(const f32x4*)(src + row * 256 + lane * 4);
  float sum = v[0] + v[1] + v[2] + v[3];
  float sq = v[0] * v[0] + v[1] * v[1] + v[2] * v[2] + v[3] * v[3];
#pragma unroll
  for (int m = 1; m < 64; m <<= 1) { sum += __shfl_xor(sum, m); sq += __shfl_xor(sq, m); }
  const float mean = sum * (1.0f / 256.0f);
  const float rs = rsqrtf(sq * (1.0f / 256.0f) - mean * mean + 1e-5f);
  const f32x4 g4 = *(const f32x4*)(gam + lane * 4);
  const f32x4 b4 = *(const f32x4*)(bet + lane * 4);
  f32x4 o;
#pragma unroll
  for (int i = 0; i < 4; ++i)
    o[i] = (v[i] - mean) * rs * g4[i] + b4[i];
  *(f32x4*)(dstf + row * 256 + lane * 4) = o;
}

extern "C" void kernel_launch(void* const* d_in, const int* in_sizes, int n_in,
                              void* d_out, int out_size, void* d_ws, size_t ws_size,
                              hipStream_t stream) {
  (void)in_sizes; (void)n_in; (void)out_size; (void)ws_size;
  const float* query = (const float*)d_in[0];
  const float* key   = (const float*)d_in[1];
  const float* value = (const float*)d_in[2];
  const float* Wq  = (const float*)d_in[3];
  const float* bq  = (const float*)d_in[4];
  const float* Wk  = (const float*)d_in[5];
  const float* bk  = (const float*)d_in[6];
  const float* Wv  = (const float*)d_in[7];
  const float* bv  = (const float*)d_in[8];
  const float* Wo  = (const float*)d_in[9];
  const float* bo  = (const float*)d_in[10];
  const float* g1  = (const float*)d_in[11];
  const float* b1  = (const float*)d_in[12];
  const float* Wff = (const float*)d_in[13];
  const float* bff = (const float*)d_in[14];
  const float* g2  = (const float*)d_in[15];
  const float* b2  = (const float*)d_in[16];

  u16* ws  = (u16*)d_ws;
  u16* WT  = ws;                      // [0, 2162688)
  u16* qb  = ws + 2162688;            // 2,097,152 each (8192x256 bf16)
  u16* kb  = ws + 4259840;
  u16* vb  = ws + 6356992;
  u16* Pq  = ws + 8454144;            // 16,777,216 each (8192x2048 bf16)
  u16* Pk  = ws + 25231360;
  u16* VT  = ws + 42008576;           // 512 groups x [d=256][q'=128]
  u16* Obuf = ws + 58785792;          // 33,554,432 B (linear gathered 8192x2048 bf16)
  u16* Pv  = Obuf;                    // same region (dead before attn writes O)
  float* part = (float*)(ws + 8454144);   // 4 x 2,097,152 f32 over Pq+Pk (dead after attn)
  u16* xbuf   = ws + 49872896;            // 2,097,152 u16 within VT region (dead after attn)
  float* tmp2 = (float*)(ws + 42008576);  // 8,388,608 B over VT start; ends before xbuf. disjoint.

  prep_kernel<<<dim3(2048, 8), 256, 0, stream>>>(query, key, value, qb, kb, vb,
                                                 Wq, Wk, Wv, Wo, Wff, WT);
  proj_kernel<<<dim3(16, 64, 3), 256, 0, stream>>>(qb, kb, vb, WT, bq, bk, bv, Pq, Pk, Pv);
  vtrans_kernel<<<dim3(8, 512), 256, 0, stream>>>(Pv, VT);
  // Dedup'd attention with ping-pong overlap schedule.
  attn_kernel<<<dim3(64, 8), 512, 0, stream>>>(Pq, Pk, VT, Obuf);
  // Wo GEMM on linear rows (M=8192), split-K=4 -> partials.
  gemm_wo_kernel<<<dim3(128, 1, 4), 256, 0, stream>>>(Obuf, WT + 1572864, part);
  reduce_ln_kernel<<<2048, 256, 0, stream>>>(part, bo, value, g1, b1, xbuf);
  gemm_ff_kernel<<<dim3(2, 128), 256, 0, stream>>>(xbuf, WT + 2097152, bff, xbuf, tmp2);
  ln2_kernel<<<2048, 256, 0, stream>>>(tmp2, g2, b2, (float*)d_out);
}

// Round 13
// 249.214 us; speedup vs baseline: 1.2227x; 1.0107x over previous
//
#include <hip/hip_runtime.h>
#include <cstdint>

typedef unsigned short u16;
typedef __attribute__((ext_vector_type(8))) short bf16x8;
typedef __attribute__((ext_vector_type(4))) float f32x4;
typedef __attribute__((ext_vector_type(4))) unsigned short u16x4;

#define AS_G __attribute__((address_space(1)))
#define AS_L __attribute__((address_space(3)))

__device__ __forceinline__ void gl_lds16(const u16* g, u16* l) {
  // async global->LDS, 16B/lane; LDS dest = wave-uniform base + lane*16
  __builtin_amdgcn_global_load_lds((const AS_G unsigned int*)g, (AS_L unsigned int*)l, 16, 0, 0);
}
__device__ __forceinline__ float bf2f(u16 u) {
  union { unsigned int i; float f; } v; v.i = ((unsigned int)u) << 16; return v.f;
}
__device__ __forceinline__ u16 f2bf(float f) {
  union { float f; unsigned int i; } v; v.f = f;
  unsigned int x = v.i;
  return (u16)((x + 0x7fffu + ((x >> 16) & 1u)) >> 16);  // RNE
}

// ---------------- merged input convert + weight pre-transpose ----------------
__global__ __launch_bounds__(256) void prep_kernel(
    const float* __restrict__ q, const float* __restrict__ k, const float* __restrict__ v,
    u16* __restrict__ qb, u16* __restrict__ kb, u16* __restrict__ vb,
    const float* __restrict__ s0, const float* __restrict__ s1, const float* __restrict__ s2,
    const float* __restrict__ s3, const float* __restrict__ s4, u16* __restrict__ wdst)
{
  const int id = blockIdx.y;
  if (id < 3) {
    const float* s = (id == 0) ? q : (id == 1) ? k : v;
    u16* d = (id == 0) ? qb : (id == 1) ? kb : vb;
    const int o = (blockIdx.x * 256 + threadIdx.x) * 4;
    const f32x4 x = *(const f32x4*)(s + o);
    u16x4 y;
#pragma unroll
    for (int i = 0; i < 4; ++i) y[i] = f2bf(x[i]);
    *(u16x4*)(d + o) = y;
  } else {
    const float* src; u16* dst; int rb, total;
    switch (id - 3) {
      case 0:  src = s0; dst = wdst;           rb = 8;  total = 524288; break;
      case 1:  src = s1; dst = wdst + 524288;  rb = 8;  total = 524288; break;
      case 2:  src = s2; dst = wdst + 1048576; rb = 8;  total = 524288; break;
      case 3:  src = s3; dst = wdst + 1572864; rb = 11; total = 524288; break;
      default: src = s4; dst = wdst + 2097152; rb = 8;  total = 65536;  break;
    }
    const int o = blockIdx.x * 256 + threadIdx.x;
    if (o >= total) return;
    const int C_ = total >> rb;
    const int c = o >> rb, r = o & ((1 << rb) - 1);
    dst[o] = f2bf(src[r * C_ + c]);
  }
}

// ---------------- QKV projection on the UNGATHERED 8192 rows ----------------
// R2 structure (best measured: 64.4 us).
__global__ __launch_bounds__(256) void proj_kernel(
    const u16* __restrict__ qb, const u16* __restrict__ kb, const u16* __restrict__ vb,
    const u16* __restrict__ wts, const float* __restrict__ bq, const float* __restrict__ bk,
    const float* __restrict__ bv, u16* __restrict__ Pq, u16* __restrict__ Pk,
    u16* __restrict__ Pv)
{
  __shared__ u16 lds[16384];            // buf b at [b*8192): A [0,4096)+B [4096,8192); epilogue: 64x136 per half
  const int t = threadIdx.x;
  const int w = t >> 6, lane = t & 63, quad = lane >> 4, lc = lane & 15;
  const int wy = w >> 1, wx = w & 1;
  // swizzle: same-by blocks (sharing the A slab) are XCD-local.
  const int flat = blockIdx.x + (blockIdx.y << 4);   // 0..1023
  const int tn = flat >> 6, by = flat & 63, z = blockIdx.z;
  const u16* A0 = ((z == 0) ? qb : (z == 1) ? kb : vb) + by * 32768;   // 128 rows x 256
  const u16* BT = wts + z * 524288 + tn * 128 * 256;

  const f32x4 fz = {0.f, 0.f, 0.f, 0.f};
  f32x4 acc[4][4];
#pragma unroll
  for (int i = 0; i < 4; ++i)
#pragma unroll
    for (int j = 0; j < 4; ++j) acc[i][j] = fz;

#define PROJ_STAGE(ck, b) do {                                         \
    const int ko_ = (ck) * 32 + w * 8;                                 \
    u16* Lb_ = &lds[(b) * 8192];                                       \
    gl_lds16(A0 + lane * 256 + ko_,        Lb_ + w * 1024);            \
    gl_lds16(A0 + (64 + lane) * 256 + ko_, Lb_ + w * 1024 + 512);      \
    gl_lds16(BT + lane * 256 + ko_,        Lb_ + 4096 + w * 1024);     \
    gl_lds16(BT + (64 + lane) * 256 + ko_, Lb_ + 4096 + w * 1024 + 512); \
  } while (0)

  PROJ_STAGE(0, 0);
#pragma unroll
  for (int ck = 0; ck < 8; ++ck) {
    const int cur = ck & 1;
    if (ck < 7) {
      PROJ_STAGE(ck + 1, cur ^ 1);
      asm volatile("s_waitcnt vmcnt(4)" ::: "memory");   // own chunk-ck loads landed; prefetch stays in flight
    } else {
      asm volatile("s_waitcnt vmcnt(0)" ::: "memory");
    }
    __builtin_amdgcn_s_barrier();                        // all waves' chunk-ck loads landed
    asm volatile("" ::: "memory");
    const u16* Ab = &lds[cur * 8192];
    const u16* Bb = &lds[cur * 8192 + 4096];
    bf16x8 af[4], bfg[4];
#pragma unroll
    for (int mi = 0; mi < 4; ++mi)
      af[mi] = *(const bf16x8*)&Ab[quad * 1024 + (wy * 64 + mi * 16 + lc) * 8];
#pragma unroll
    for (int ni = 0; ni < 4; ++ni)
      bfg[ni] = *(const bf16x8*)&Bb[quad * 1024 + (wx * 64 + ni * 16 + lc) * 8];
#pragma unroll
    for (int mi = 0; mi < 4; ++mi)
#pragma unroll
      for (int ni = 0; ni < 4; ++ni)
        acc[mi][ni] = __builtin_amdgcn_mfma_f32_16x16x32_bf16(af[mi], bfg[ni], acc[mi][ni], 0, 0, 0);
    asm volatile("s_waitcnt lgkmcnt(0)" ::: "memory");   // all ds_reads of buf[cur] done
    __builtin_amdgcn_s_barrier();                        // safe to overwrite buf[cur] next iter
  }
#undef PROJ_STAGE

  const float* bias = (z == 0) ? bq : (z == 1) ? bk : bv;
  u16* P = ((z == 0) ? Pq : (z == 1) ? Pk : Pv) + by * 262144;

  // Two 64-row epilogue passes; each uses only 64x136 u16 = 17408 B of LDS.
#pragma unroll
  for (int half = 0; half < 2; ++half) {
    __syncthreads();                     // prev pass reads / K-loop staging done
    if (wy == half) {
#pragma unroll
      for (int mi = 0; mi < 4; ++mi)
#pragma unroll
        for (int ni = 0; ni < 4; ++ni) {
          const int col = wx * 64 + ni * 16 + lc;
          const float bi = bias[tn * 128 + col];
#pragma unroll
          for (int r = 0; r < 4; ++r) {
            const int row = mi * 16 + quad * 4 + r;
            lds[row * 136 + col] = f2bf(acc[mi][ni][r] + bi);
          }
        }
    }
    __syncthreads();
#pragma unroll
    for (int p = 0; p < 4; ++p) {        // 256B-contiguous row segments, 16B/lane
      const int e = p * 2048 + t * 8;
      const int row = e >> 7, col0 = e & 127;
      *(bf16x8*)(P + (half * 64 + row) * 2048 + tn * 128 + col0) =
          *(const bf16x8*)&lds[row * 136 + col0];
    }
  }
}

// ---------------- Pv group-slab transpose (coalesced both sides) ----------------
__global__ __launch_bounds__(256) void vtrans_kernel(
    const u16* __restrict__ Pv, u16* __restrict__ VT)
{
  __shared__ u16 lT[4096];
  const int t = threadIdx.x;
  const int tile = blockIdx.x;          // 0..7
  const int g = blockIdx.y;             // 0..511
  const int q0 = (tile & 1) * 64, d0 = (tile >> 1) * 64;
  const u16* src = Pv + g * 32768;      // [q'=128][d=256]
  u16* dst = VT + g * 32768;            // [d=256][q'=128]
#pragma unroll
  for (int it = 0; it < 2; ++it) {
    const int e = it * 2048 + t * 8;
    const int lq = e >> 6, ld0 = e & 63;
    const bf16x8 v = *(const bf16x8*)(src + (q0 + lq) * 256 + d0 + ld0);
    const int kb = ((ld0 >> 3) + lq + (lq >> 3)) & 7;
    *(bf16x8*)&lT[lq * 64 + kb * 8] = v;
  }
  __syncthreads();
#pragma unroll
  for (int it = 0; it < 2; ++it) {
    const int e = it * 2048 + t * 8;
    const int ld = e >> 6, lq0 = e & 63;
    bf16x8 v;
#pragma unroll
    for (int i = 0; i < 8; ++i) {
      const int lq = lq0 + i;
      const int kb = ((ld >> 3) + lq + (lq >> 3)) & 7;
      v[i] = (short)lT[lq * 64 + kb * 8 + (ld & 7)];
    }
    *(bf16x8*)(dst + (d0 + ld) * 128 + q0 + lq0) = v;
  }
}

// ---------------- attention per DISTINCT unit (dedup'd, R11 ping-pong) ----------------
// R11 verbatim (measured-good, 251.9 total). The R12 vtrans-deletion via
// ds_read_b64_tr_b16 FAILED refcheck (absmax 0.176) -> reverted per the
// pre-committed falsifier.
__global__ __launch_bounds__(512) void attn_kernel(
    const u16* __restrict__ Pq, const u16* __restrict__ Pk,
    const u16* __restrict__ VT, u16* __restrict__ Obuf)
{
  __shared__ u16 bufA[16384];
  __shared__ u16 bufB[16384];
  const int t = threadIdx.x;
  const int w = t >> 6, lane = t & 63, quad = lane >> 4, lc = lane & 15;
  const int M = blockIdx.x, b = blockIdx.y;
  const int m0 = w * 16;
  const int r0 = b * 1024 + M * 16;
  const u16* Qb = Pq + r0 * 2048;
  const u16* Kb = Pk + r0 * 2048;
  const u16* Vb = VT + (b * 64 + M) * 32768;
  const f32x4 fz = {0.f, 0.f, 0.f, 0.f};

  bf16x8 aq[8];
#pragma unroll
  for (int kc = 0; kc < 8; ++kc)
    aq[kc] = *(const bf16x8*)(Qb + (m0 + lc) * 256 + kc * 32 + quad * 8);

  // stage K0 (rows 0..63) -> bufA
#pragma unroll
  for (int jj = 0; jj < 4; ++jj)
    gl_lds16(Kb + lane * 256 + w * 32 + jj * 8, &bufA[w * 2048 + jj * 512]);
  asm volatile("s_waitcnt vmcnt(0)" ::: "memory");       // K0 (and aq) landed
  __builtin_amdgcn_s_barrier();
  asm volatile("" ::: "memory");

  f32x4 s[8];
  // phase 1: stage K1 (rows 64..127) -> bufB, compute QK0 from bufA
#pragma unroll
  for (int jj = 0; jj < 4; ++jj)
    gl_lds16(Kb + (64 + lane) * 256 + w * 32 + jj * 8, &bufB[w * 2048 + jj * 512]);
#pragma unroll
  for (int ntl = 0; ntl < 4; ++ntl) {
    s[ntl] = fz;
#pragma unroll
    for (int kc = 0; kc < 8; ++kc) {
      const bf16x8 bfr = *(const bf16x8*)&bufA[kc * 2048 + quad * 512 + (ntl * 16 + lc) * 8];
      s[ntl] = __builtin_amdgcn_mfma_f32_16x16x32_bf16(aq[kc], bfr, s[ntl], 0, 0, 0);
    }
  }
  asm volatile("s_waitcnt vmcnt(0)" ::: "memory");       // K1 landed
  __builtin_amdgcn_s_barrier();
  asm volatile("" ::: "memory");

  // phase 2: compute QK1 from bufB
#pragma unroll
  for (int ntl = 0; ntl < 4; ++ntl) {
    s[4 + ntl] = fz;
#pragma unroll
    for (int kc = 0; kc < 8; ++kc) {
      const bf16x8 bfr = *(const bf16x8*)&bufB[kc * 2048 + quad * 512 + (ntl * 16 + lc) * 8];
      s[4 + ntl] = __builtin_amdgcn_mfma_f32_16x16x32_bf16(aq[kc], bfr, s[4 + ntl], 0, 0, 0);
    }
  }
  __builtin_amdgcn_s_barrier();                          // all K1 reads consumed -> bufB free
  asm volatile("" ::: "memory");

  // stage V0 -> bufB (latency hides under softmax)
#pragma unroll
  for (int jj = 0; jj < 4; ++jj) {
    const int i = w * 4 + jj;
    const int kc2l = i >> 4, cb = (i >> 2) & 3, db = (i & 3) * 64;
    gl_lds16(Vb + (db + lane) * 128 + kc2l * 32 + cb * 8,
             &bufB[kc2l * 8192 + cb * 2048 + db * 8]);
  }

  // softmax; P-writes -> bufA (K0 dead since barrier after phase 1)
  const float scale = 0.0625f;
#pragma unroll
  for (int r = 0; r < 4; ++r) {
    float mx = -3.0e38f;
#pragma unroll
    for (int nt = 0; nt < 8; ++nt) mx = fmaxf(mx, s[nt][r]);
    mx = fmaxf(mx, __shfl_xor(mx, 1)); mx = fmaxf(mx, __shfl_xor(mx, 2));
    mx = fmaxf(mx, __shfl_xor(mx, 4)); mx = fmaxf(mx, __shfl_xor(mx, 8));
    mx *= scale;
    float sm = 0.0f;
#pragma unroll
    for (int nt = 0; nt < 8; ++nt) {
      const float e = __expf(s[nt][r] * scale - mx);
      s[nt][r] = e; sm += e;
    }
    sm += __shfl_xor(sm, 1); sm += __shfl_xor(sm, 2);
    sm += __shfl_xor(sm, 4); sm += __shfl_xor(sm, 8);
    const float inv = 1.0f / sm;
    const int q = m0 + quad * 4 + r;
#pragma unroll
    for (int nt = 0; nt < 8; ++nt) {
      const int k = nt * 16 + lc;
      bufA[(k >> 5) * 4096 + ((k >> 3) & 3) * 1024 + q * 8 + (k & 7)] = f2bf(s[nt][r] * inv);
    }
  }
  asm volatile("s_waitcnt lgkmcnt(0)" ::: "memory");     // own P ds_writes retired
  __builtin_amdgcn_s_barrier();                          // P visible to all
  asm volatile("" ::: "memory");

  // ap <- P from bufA
  bf16x8 ap[4];
#pragma unroll
  for (int kc2 = 0; kc2 < 4; ++kc2)
    ap[kc2] = *(const bf16x8*)&bufA[kc2 * 4096 + quad * 1024 + (m0 + lc) * 8];
  asm volatile("s_waitcnt vmcnt(0) lgkmcnt(0)" ::: "memory");  // V0 landed; ap in regs
  __builtin_amdgcn_s_barrier();                          // bufA free for V1; bufB(V0) ready
  asm volatile("" ::: "memory");

  f32x4 o[16];
#pragma unroll
  for (int nt = 0; nt < 16; ++nt) o[nt] = fz;

  // phase 4: stage V1 -> bufA, compute PV0 (ap[0..1] x bufB)
#pragma unroll
  for (int jj = 0; jj < 4; ++jj) {
    const int i = w * 4 + jj;
    const int kc2l = i >> 4, cb = (i >> 2) & 3, db = (i & 3) * 64;
    gl_lds16(Vb + (db + lane) * 128 + (2 + kc2l) * 32 + cb * 8,
             &bufA[kc2l * 8192 + cb * 2048 + db * 8]);
  }
#pragma unroll
  for (int nt = 0; nt < 16; ++nt)
#pragma unroll
    for (int kc2l = 0; kc2l < 2; ++kc2l) {
      const bf16x8 bfr = *(const bf16x8*)&bufB[kc2l * 8192 + quad * 2048 + (nt * 16 + lc) * 8];
      o[nt] = __builtin_amdgcn_mfma_f32_16x16x32_bf16(ap[kc2l], bfr, o[nt], 0, 0, 0);
    }
  asm volatile("s_waitcnt vmcnt(0)" ::: "memory");       // V1 landed
  __builtin_amdgcn_s_barrier();
  asm volatile("" ::: "memory");

  // phase 5: compute PV1 (ap[2..3] x bufA)
#pragma unroll
  for (int nt = 0; nt < 16; ++nt)
#pragma unroll
    for (int kc2l = 0; kc2l < 2; ++kc2l) {
      const bf16x8 bfr = *(const bf16x8*)&bufA[kc2l * 8192 + quad * 2048 + (nt * 16 + lc) * 8];
      o[nt] = __builtin_amdgcn_mfma_f32_16x16x32_bf16(ap[2 + kc2l], bfr, o[nt], 0, 0, 0);
    }

  u16* Ob = Obuf + r0 * 2048;           // linear gathered output rows [16M,16M+16)
#pragma unroll
  for (int nt = 0; nt < 16; ++nt)
#pragma unroll
    for (int r = 0; r < 4; ++r) {
      const int q = m0 + quad * 4 + r;
      Ob[q * 256 + nt * 16 + lc] = f2bf(o[nt][r]);
    }
}

// ---------------- Wo GEMM (M=8192), split-K=4, bf16 partials ----------------
// NEW (this round): partials stored as bf16 (not f32) -> halves the 67 MB
// partial round-trip. Precision: partial magnitude ~0.3, bf16 rel err 2^-9
// -> ~1e-3 absolute per partial, far under the 0.099 threshold.
__global__ __launch_bounds__(256) void gemm_wo_kernel(
    const u16* __restrict__ A, const u16* __restrict__ BT, u16* __restrict__ outb)
{
  __shared__ u16 lA[2][2048];           // [ks=4][64 rows][8]
  __shared__ u16 lB[2][8192];           // [ks=4][256 rows][8]
  const int t = threadIdx.x;
  const int w = t >> 6, lane = t & 63, quad = lane >> 4, lc = lane & 15;
  const int bb = blockIdx.x, kz = blockIdx.z;
  const int k0 = kz * 512;              // kslice = 2048/4
  const u16* Arow = A + (bb * 64 + lane) * 2048 + k0;
  const u16* BT0 = BT + k0;

  const f32x4 fz = {0.f, 0.f, 0.f, 0.f};
  f32x4 acc[4][4];
#pragma unroll
  for (int i = 0; i < 4; ++i)
#pragma unroll
    for (int jj = 0; jj < 4; ++jj) acc[i][jj] = fz;

#define GWO_STAGE(ck, b) do {                                          \
    const int ko_ = (ck) * 32 + w * 8;                                 \
    gl_lds16(Arow + ko_, &lA[b][w * 512]);                             \
    _Pragma("unroll")                                                  \
    for (int sg_ = 0; sg_ < 4; ++sg_)                                  \
      gl_lds16(BT0 + (sg_ * 64 + lane) * 2048 + ko_,                   \
               &lB[b][w * 2048 + sg_ * 512]);                          \
  } while (0)

  GWO_STAGE(0, 0);
  for (int ck = 0; ck < 16; ++ck) {
    const int cur = ck & 1;
    if (ck < 15) {
      GWO_STAGE(ck + 1, cur ^ 1);
      asm volatile("s_waitcnt vmcnt(5)" ::: "memory");
    } else {
      asm volatile("s_waitcnt vmcnt(0)" ::: "memory");
    }
    __builtin_amdgcn_s_barrier();
    asm volatile("" ::: "memory");
    bf16x8 af[4], bfg[4];
#pragma unroll
    for (int mi = 0; mi < 4; ++mi)
      af[mi] = *(const bf16x8*)&lA[cur][quad * 512 + (mi * 16 + lc) * 8];
#pragma unroll
    for (int ni = 0; ni < 4; ++ni) {
      const int cl = w * 64 + ni * 16 + lc;
      bfg[ni] = *(const bf16x8*)&lB[cur][quad * 2048 + cl * 8];
    }
#pragma unroll
    for (int mi = 0; mi < 4; ++mi)
#pragma unroll
      for (int ni = 0; ni < 4; ++ni)
        acc[mi][ni] = __builtin_amdgcn_mfma_f32_16x16x32_bf16(af[mi], bfg[ni], acc[mi][ni], 0, 0, 0);
    asm volatile("s_waitcnt lgkmcnt(0)" ::: "memory");
    __builtin_amdgcn_s_barrier();
  }
#undef GWO_STAGE

  u16* O = outb + kz * 2097152 + bb * 64 * 256;
#pragma unroll
  for (int mi = 0; mi < 4; ++mi)
#pragma unroll
    for (int ni = 0; ni < 4; ++ni) {
      const int cg = w * 64 + ni * 16 + lc;
#pragma unroll
      for (int r = 0; r < 4; ++r)
        O[(mi * 16 + quad * 4 + r) * 256 + cg] = f2bf(acc[mi][ni][r]);
    }
}

// ---------------- FF GEMM (64x128 tile, K=256, fused bias+resid epilogue) ----------------
__global__ __launch_bounds__(256) void gemm_ff_kernel(
    const u16* __restrict__ A, const u16* __restrict__ BT, const float* __restrict__ bias,
    const u16* __restrict__ residb, float* __restrict__ out)
{
  __shared__ u16 lA[2][2048];
  __shared__ u16 lB[2][4096];
  const int t = threadIdx.x;
  const int w = t >> 6, lane = t & 63, quad = lane >> 4, lc = lane & 15;
  const int tn = blockIdx.x, bb = blockIdx.y;
  const u16* A0 = A + bb * 64 * 256;
  const u16* BT0 = BT + tn * 128 * 256;

  const f32x4 fz = {0.f, 0.f, 0.f, 0.f};
  f32x4 acc[4][2];
#pragma unroll
  for (int i = 0; i < 4; ++i) { acc[i][0] = fz; acc[i][1] = fz; }

#define GFF_STAGE(ck, b) do {                                          \
    const int ko_ = (ck) * 32 + w * 8;                                 \
    gl_lds16(A0 + lane * 256 + ko_,        &lA[b][w * 512]);           \
    gl_lds16(BT0 + lane * 256 + ko_,       &lB[b][w * 1024]);          \
    gl_lds16(BT0 + (64 + lane) * 256 + ko_, &lB[b][w * 1024 + 512]);   \
  } while (0)

  GFF_STAGE(0, 0);
  for (int ck = 0; ck < 8; ++ck) {
    const int cur = ck & 1;
    if (ck < 7) {
      GFF_STAGE(ck + 1, cur ^ 1);
      asm volatile("s_waitcnt vmcnt(3)" ::: "memory");
    } else {
      asm volatile("s_waitcnt vmcnt(0)" ::: "memory");
    }
    __builtin_amdgcn_s_barrier();
    asm volatile("" ::: "memory");
    bf16x8 af[4], bfg[2];
#pragma unroll
    for (int mi = 0; mi < 4; ++mi)
      af[mi] = *(const bf16x8*)&lA[cur][quad * 512 + (mi * 16 + lc) * 8];
#pragma unroll
    for (int ni = 0; ni < 2; ++ni) {
      const int cl = w * 32 + ni * 16 + lc;
      bfg[ni] = *(const bf16x8*)&lB[cur][quad * 1024 + (cl >> 6) * 512 + (cl & 63) * 8];
    }
#pragma unroll
    for (int mi = 0; mi < 4; ++mi)
#pragma unroll
      for (int ni = 0; ni < 2; ++ni)
        acc[mi][ni] = __builtin_amdgcn_mfma_f32_16x16x32_bf16(af[mi], bfg[ni], acc[mi][ni], 0, 0, 0);
    asm volatile("s_waitcnt lgkmcnt(0)" ::: "memory");
    __builtin_amdgcn_s_barrier();
  }
#undef GFF_STAGE

#pragma unroll
  for (int mi = 0; mi < 4; ++mi)
#pragma unroll
    for (int ni = 0; ni < 2; ++ni) {
      const int cg = tn * 128 + w * 32 + ni * 16 + lc;
      const float bi = bias[cg];
#pragma unroll
      for (int r = 0; r < 4; ++r) {
        const int rl = mi * 16 + quad * 4 + r;
        const float res = bf2f(residb[(bb * 64 + rl) * 256 + cg]);
        out[(bb * 64 + rl) * 256 + cg] = acc[mi][ni][r] + bi + res;
      }
    }
}

// ---------------- fused split-K reduce (bf16 partials) + bias + value-resid + LN1 ----------------
__global__ __launch_bounds__(256) void reduce_ln_kernel(
    const u16* __restrict__ partb, const float* __restrict__ bias,
    const float* __restrict__ value, const float* __restrict__ gam,
    const float* __restrict__ bet, u16* __restrict__ dstb)
{
  const int t = threadIdx.x, w = t >> 6, lane = t & 63;
  const int row = blockIdx.x * 4 + w;
  const int e = row * 256 + lane * 4;
  const int col = lane * 4;
  f32x4 s = {0.f, 0.f, 0.f, 0.f};
#pragma unroll
  for (int p = 0; p < 4; ++p) {
    const u16x4 v = *(const u16x4*)(partb + p * 2097152 + e);
#pragma unroll
    for (int i = 0; i < 4; ++i) s[i] += bf2f(v[i]);
  }
  const f32x4 bi = *(const f32x4*)(bias + col);
  const f32x4 rv = *(const f32x4*)(value + e);
#pragma unroll
  for (int i = 0; i < 4; ++i) s[i] += bi[i] + rv[i];
  float sum = s[0] + s[1] + s[2] + s[3];
  float sq = s[0] * s[0] + s[1] * s[1] + s[2] * s[2] + s[3] * s[3];
#pragma unroll
  for (int m = 1; m < 64; m <<= 1) { sum += __shfl_xor(sum, m); sq += __shfl_xor(sq, m); }
  const float mean = sum * (1.0f / 256.0f);
  const float rs = rsqrtf(sq * (1.0f / 256.0f) - mean * mean + 1e-5f);
  const f32x4 g4 = *(const f32x4*)(gam + col);
  const f32x4 b4 = *(const f32x4*)(bet + col);
  u16x4 ob;
#pragma unroll
  for (int i = 0; i < 4; ++i) ob[i] = f2bf((s[i] - mean) * rs * g4[i] + b4[i]);
  *(u16x4*)(dstb + row * 256 + lane * 4) = ob;
}

// ---------------- final layernorm -> d_out ----------------
__global__ __launch_bounds__(256) void ln2_kernel(
    const float* __restrict__ src, const float* __restrict__ gam, const float* __restrict__ bet,
    float* __restrict__ dstf)
{
  const int t = threadIdx.x, w = t >> 6, lane = t & 63;
  const int row = blockIdx.x * 4 + w;
  const f32x4 v = *(const f32x4*)(src + row * 256 + lane * 4);
  float sum = v[0] + v[1] + v[2] + v[3];
  float sq = v[0] * v[0] + v[1] * v[1] + v[2] * v[2] + v[3] * v[3];
#pragma unroll
  for (int m = 1; m < 64; m <<= 1) { sum += __shfl_xor(sum, m); sq += __shfl_xor(sq, m); }
  const float mean = sum * (1.0f / 256.0f);
  const float rs = rsqrtf(sq * (1.0f / 256.0f) - mean * mean + 1e-5f);
  const f32x4 g4 = *(const f32x4*)(gam + lane * 4);
  const f32x4 b4 = *(const f32x4*)(bet + lane * 4);
  f32x4 o;
#pragma unroll
  for (int i = 0; i < 4; ++i)
    o[i] = (v[i] - mean) * rs * g4[i] + b4[i];
  *(f32x4*)(dstf + row * 256 + lane * 4) = o;
}

extern "C" void kernel_launch(void* const* d_in, const int* in_sizes, int n_in,
                              void* d_out, int out_size, void* d_ws, size_t ws_size,
                              hipStream_t stream) {
  (void)in_sizes; (void)n_in; (void)out_size; (void)ws_size;
  const float* query = (const float*)d_in[0];
  const float* key   = (const float*)d_in[1];
  const float* value = (const float*)d_in[2];
  const float* Wq  = (const float*)d_in[3];
  const float* bq  = (const float*)d_in[4];
  const float* Wk  = (const float*)d_in[5];
  const float* bk  = (const float*)d_in[6];
  const float* Wv  = (const float*)d_in[7];
  const float* bv  = (const float*)d_in[8];
  const float* Wo  = (const float*)d_in[9];
  const float* bo  = (const float*)d_in[10];
  const float* g1  = (const float*)d_in[11];
  const float* b1  = (const float*)d_in[12];
  const float* Wff = (const float*)d_in[13];
  const float* bff = (const float*)d_in[14];
  const float* g2  = (const float*)d_in[15];
  const float* b2  = (const float*)d_in[16];

  u16* ws  = (u16*)d_ws;
  u16* WT  = ws;                      // [0, 2162688)
  u16* qb  = ws + 2162688;            // 2,097,152 each (8192x256 bf16)
  u16* kb  = ws + 4259840;
  u16* vb  = ws + 6356992;
  u16* Pq  = ws + 8454144;            // 16,777,216 each (8192x2048 bf16)
  u16* Pk  = ws + 25231360;
  u16* VT  = ws + 42008576;           // 512 groups x [d=256][q'=128]
  u16* Obuf = ws + 58785792;          // 33,554,432 B (linear gathered 8192x2048 bf16)
  u16* Pv  = Obuf;                    // same region (dead before attn writes O)
  u16* partb = ws + 8454144;              // 4 x 2,097,152 u16 bf16 partials over Pq (dead after attn)
  u16* xbuf  = ws + 49872896;             // 2,097,152 u16 within VT region (dead after attn)
  float* tmp2 = (float*)(ws + 42008576);  // 8,388,608 B over VT start; ends before xbuf. disjoint.

  prep_kernel<<<dim3(2048, 8), 256, 0, stream>>>(query, key, value, qb, kb, vb,
                                                 Wq, Wk, Wv, Wo, Wff, WT);
  proj_kernel<<<dim3(16, 64, 3), 256, 0, stream>>>(qb, kb, vb, WT, bq, bk, bv, Pq, Pk, Pv);
  vtrans_kernel<<<dim3(8, 512), 256, 0, stream>>>(Pv, VT);
  // Dedup'd attention with ping-pong overlap schedule (R11).
  attn_kernel<<<dim3(64, 8), 512, 0, stream>>>(Pq, Pk, VT, Obuf);
  // Wo GEMM on linear rows (M=8192), split-K=4 -> bf16 partials.
  gemm_wo_kernel<<<dim3(128, 1, 4), 256, 0, stream>>>(Obuf, WT + 1572864, partb);
  reduce_ln_kernel<<<2048, 256, 0, stream>>>(partb, bo, value, g1, b1, xbuf);
  gemm_ff_kernel<<<dim3(2, 128), 256, 0, stream>>>(xbuf, WT + 2097152, bff, xbuf, tmp2);
  ln2_kernel<<<2048, 256, 0, stream>>>(tmp2, g2, b2, (float*)d_out);
}